// Round 4
// baseline (445.271 us; speedup 1.0000x reference)
//
#include <hip/hip_runtime.h>
#include <hip/hip_bf16.h>

#define B_   2
#define T_   2048
#define D_   2048
#define NH_  16
#define NKV_ 4
#define HD_  128
#define KD_  512   // NKV*HD
#define BT_  4096  // B_*T_

typedef __bf16 bf16x8 __attribute__((ext_vector_type(8)));
typedef float  f32x4  __attribute__((ext_vector_type(4)));
typedef float  f32x16 __attribute__((ext_vector_type(16)));

__device__ __forceinline__ void gload_lds16(const __hip_bfloat16* g, __hip_bfloat16* l) {
    __builtin_amdgcn_global_load_lds(
        (__attribute__((address_space(1))) void*)(g),
        (__attribute__((address_space(3))) void*)(l),
        16, 0, 0);
}

// ---------------- fp32 -> bf16 convert ----------------
__global__ void f2b_kernel(const float4* __restrict__ in, ushort4* __restrict__ out, int n4) {
    int idx = blockIdx.x * blockDim.x + threadIdx.x;
    int stride = gridDim.x * blockDim.x;
    for (int j = idx; j < n4; j += stride) {
        float4 v = in[j];
        __hip_bfloat16 a = __float2bfloat16(v.x), b = __float2bfloat16(v.y),
                       c = __float2bfloat16(v.z), d = __float2bfloat16(v.w);
        ushort4 o;
        o.x = *(const unsigned short*)&a; o.y = *(const unsigned short*)&b;
        o.z = *(const unsigned short*)&c; o.w = *(const unsigned short*)&d;
        out[j] = o;
    }
}

// ---------------- GEMM: C(MxN) = A(MxK) * B(NxK)^T, bf16 in, f32 out ----------------
__global__ __launch_bounds__(256)
void gemm_bt(const __hip_bfloat16* __restrict__ A, const __hip_bfloat16* __restrict__ B,
             float* __restrict__ C, int M, int N, int K) {
    __shared__ __attribute__((aligned(16))) __hip_bfloat16 As[128 * 32];
    __shared__ __attribute__((aligned(16))) __hip_bfloat16 Bs[128 * 32];
    const int tid  = threadIdx.x;
    const int w    = tid >> 6;
    const int lane = tid & 63;
    const int lr   = lane & 15;
    const int lk   = lane >> 4;
    const int wr   = w >> 1, wc = w & 1;
    const size_t row0 = (size_t)blockIdx.x * 128;
    const size_t col0 = (size_t)blockIdx.y * 128;

    const __hip_bfloat16* ga = A + (row0 + tid / 4) * K + (tid % 4) * 8;
    const __hip_bfloat16* gb = B + (col0 + tid / 4) * K + (tid % 4) * 8;
    __hip_bfloat16* lA0 = &As[w * 512];
    __hip_bfloat16* lA1 = &As[2048 + w * 512];
    __hip_bfloat16* lB0 = &Bs[w * 512];
    __hip_bfloat16* lB1 = &Bs[2048 + w * 512];

    f32x4 acc[4][4] = {};
    for (int k0 = 0; k0 < K; k0 += 32) {
        gload_lds16(ga + k0,                 lA0);
        gload_lds16(ga + k0 + (size_t)64*K,  lA1);
        gload_lds16(gb + k0,                 lB0);
        gload_lds16(gb + k0 + (size_t)64*K,  lB1);
        __syncthreads();
        bf16x8 af[4], bfr[4];
        #pragma unroll
        for (int m = 0; m < 4; m++)
            af[m] = *(const bf16x8*)&As[(wr * 64 + m * 16 + lr) * 32 + lk * 8];
        #pragma unroll
        for (int n = 0; n < 4; n++)
            bfr[n] = *(const bf16x8*)&Bs[(wc * 64 + n * 16 + lr) * 32 + lk * 8];
        #pragma unroll
        for (int m = 0; m < 4; m++)
            #pragma unroll
            for (int n = 0; n < 4; n++)
                acc[m][n] = __builtin_amdgcn_mfma_f32_16x16x32_bf16(af[m], bfr[n], acc[m][n], 0, 0, 0);
        __syncthreads();
    }
    #pragma unroll
    for (int m = 0; m < 4; m++)
        #pragma unroll
        for (int n = 0; n < 4; n++)
            #pragma unroll
            for (int r = 0; r < 4; r++)
                C[(row0 + wr * 64 + m * 16 + lk * 4 + r) * N + col0 + wc * 64 + n * 16 + lr] = acc[m][n][r];
}

// ---------------- RMSNorm + partial RoPE + gain; v passthrough to bf16 ----------------
__global__ __launch_bounds__(256)
void norm_rope(const float* __restrict__ qf, const float* __restrict__ kf, const float* __restrict__ vf,
               const float* __restrict__ qg,
               __hip_bfloat16* __restrict__ qb, __hip_bfloat16* __restrict__ kb, __hip_bfloat16* __restrict__ vb) {
    int wid  = (blockIdx.x * 256 + threadIdx.x) >> 6;
    int lane = threadIdx.x & 63;
    int bt = wid / 24, hh = wid % 24;
    int b = bt >> 11, t = bt & (T_ - 1);

    const float* row;
    if (hh < NH_)            row = qf + (size_t)bt * D_  + hh * HD_;
    else if (hh < NH_+NKV_)  row = kf + (size_t)bt * KD_ + (hh - NH_) * HD_;
    else                     row = vf + (size_t)bt * KD_ + (hh - NH_ - NKV_) * HD_;

    float2 xv = *(const float2*)(row + lane * 2);

    if (hh >= NH_ + NKV_) {  // v: just convert
        int kv = hh - NH_ - NKV_;
        __hip_bfloat16* o = vb + ((size_t)(b * NKV_ + kv) * T_ + t) * HD_ + lane * 2;
        o[0] = __float2bfloat16(xv.x); o[1] = __float2bfloat16(xv.y);
        return;
    }

    float ss = xv.x * xv.x + xv.y * xv.y;
    #pragma unroll
    for (int off = 32; off; off >>= 1) ss += __shfl_xor(ss, off);
    float rn = rsqrtf(ss * (1.0f / HD_) + 1.1920929e-7f);
    float y0 = xv.x * rn, y1 = xv.y * rn;

    float py0 = __shfl_xor(y0, 4), py1 = __shfl_xor(y1, 4);
    float o0 = y0, o1 = y1;
    if (lane < 8) {
        int i0 = (2 * lane) & 7;
        float f0 = (float)t * exp2f(-(float)i0       * 1.66096404744368f);
        float f1 = (float)t * exp2f(-(float)(i0 + 1) * 1.66096404744368f);
        float s0, c0, s1, c1;
        sincosf(f0, &s0, &c0);
        sincosf(f1, &s1, &c1);
        if (lane < 4) { o0 =  y0 * c0 + py0 * s0; o1 =  y1 * c1 + py1 * s1; }
        else          { o0 = -y0 * c0 + py0 * s0; o1 = -y1 * c1 + py1 * s1; }
    }

    if (hh < NH_) {
        // fold gain * 1/sqrt(HD) * log2(e) into q
        float g = qg[hh] * 0.1275174305f;
        o0 *= g; o1 *= g;
        __hip_bfloat16* o = qb + ((size_t)(b * NH_ + hh) * T_ + t) * HD_ + lane * 2;
        o[0] = __float2bfloat16(o0); o[1] = __float2bfloat16(o1);
    } else {
        int kv = hh - NH_;
        __hip_bfloat16* o = kb + ((size_t)(b * NKV_ + kv) * T_ + t) * HD_ + lane * 2;
        o[0] = __float2bfloat16(o0); o[1] = __float2bfloat16(o1);
    }
}

// ---------------- V transpose: [bk][T][HD] -> [bk][HD][T] ----------------
__global__ void vtrans(const __hip_bfloat16* __restrict__ vb, __hip_bfloat16* __restrict__ vt) {
    __shared__ __hip_bfloat16 tile[32][33];
    int bk = blockIdx.z;
    int t0 = blockIdx.x * 32, h0 = blockIdx.y * 32;
    int tx = threadIdx.x, ty = threadIdx.y;  // 32 x 8
    const __hip_bfloat16* src = vb + ((size_t)bk * T_ + t0) * HD_ + h0;
    #pragma unroll
    for (int j = 0; j < 4; j++) tile[ty + j * 8][tx] = src[(size_t)(ty + j * 8) * HD_ + tx];
    __syncthreads();
    __hip_bfloat16* dst = vt + ((size_t)bk * HD_ + h0) * T_ + t0;
    #pragma unroll
    for (int j = 0; j < 4; j++) dst[(size_t)(ty + j * 8) * T_ + tx] = tile[tx][ty + j * 8];
}

// ---------------- causal GQA flash attention ----------------
// Block = 512 threads = 8 waves per 32-row q-chunk:
//   wave = (seg, dh): seg in 0..3 processes KV tiles kt == seg (mod 4);
//   dh in 0..1 owns d-dims [dh*64, dh*64+64) for PV (QK+softmax duplicated).
// Cross-segment merge of (m, s, O) via LDS tree at the end.
__device__ __forceinline__ unsigned pkbf(float a, float b) {
    __hip_bfloat16 x = __float2bfloat16(a), y = __float2bfloat16(b);
    unsigned short xu = *(const unsigned short*)&x, yu = *(const unsigned short*)&y;
    return (unsigned)xu | ((unsigned)yu << 16);
}

union U8u { unsigned u[4]; bf16x8 v; };

__global__ __launch_bounds__(512, 4)
void attn_fwd(const __hip_bfloat16* __restrict__ qb, const __hip_bfloat16* __restrict__ kb,
              const __hip_bfloat16* __restrict__ vt, __hip_bfloat16* __restrict__ yb) {
    __shared__ float lO[2][2][32 * 64];   // [dh][buf][r*64 + lane]
    __shared__ float lms[2][2][64];       // [buf][m|s][lane]
    const int tid  = threadIdx.x;
    const int w    = tid >> 6, lane = tid & 63;
    const int seg  = w & 3, dh = w >> 2;
    const int l31  = lane & 31, hi = lane >> 5;
    const int bid  = blockIdx.x;
    const int xcd  = bid & 7;              // = b*4 + kvh (XCD-grouped K/V reuse)
    const int b    = xcd >> 2, kvh = xcd & 3;
    const int idx  = bid >> 3;             // 0..255
    const int g    = idx & 3;
    const int h    = kvh * 4 + g;
    const int c    = 63 - (idx >> 2);      // LPT: longest chunks first
    const int qa   = c * 32;

    const __hip_bfloat16* qp = qb + ((size_t)(b * NH_ + h) * T_ + qa) * HD_;
    const __hip_bfloat16* kp = kb + (size_t)(b * NKV_ + kvh) * T_ * HD_;
    const __hip_bfloat16* vp = vt + ((size_t)(b * NKV_ + kvh) * HD_ + dh * 64 + l31) * T_;

    bf16x8 qfr[8];
    #pragma unroll
    for (int hb = 0; hb < 8; ++hb)
        qfr[hb] = *(const bf16x8*)(qp + (size_t)l31 * HD_ + hb * 16 + hi * 8);

    f32x16 o0 = {}, o1 = {};
    float m = -1e30f, s = 0.f;

    for (int kt = seg; kt <= c; kt += 4) {
        const int kvb = kt * 32;
        const __hip_bfloat16* kpt = kp + (size_t)(kvb + l31) * HD_ + hi * 8;
        // S^T[kv][q] = sum_hd K[kv][hd] * Q[q][hd]  (two half-batches to cap reg peak)
        f32x16 sa = {};
        {
            bf16x8 kf[4];
            #pragma unroll
            for (int hb = 0; hb < 4; ++hb) kf[hb] = *(const bf16x8*)(kpt + hb * 16);
            __builtin_amdgcn_s_setprio(1);
            #pragma unroll
            for (int hb = 0; hb < 4; ++hb)
                sa = __builtin_amdgcn_mfma_f32_32x32x16_bf16(kf[hb], qfr[hb], sa, 0, 0, 0);
            __builtin_amdgcn_s_setprio(0);
        }
        {
            bf16x8 kf[4];
            #pragma unroll
            for (int hb = 0; hb < 4; ++hb) kf[hb] = *(const bf16x8*)(kpt + 64 + hb * 16);
            __builtin_amdgcn_s_setprio(1);
            #pragma unroll
            for (int hb = 0; hb < 4; ++hb)
                sa = __builtin_amdgcn_mfma_f32_32x32x16_bf16(kf[hb], qfr[4 + hb], sa, 0, 0, 0);
            __builtin_amdgcn_s_setprio(0);
        }
        if (kt == c) {  // diagonal tile: mask kv > q (relative indices)
            #pragma unroll
            for (int r = 0; r < 16; ++r) {
                int kvrel = (r & 3) + 8 * (r >> 2) + 4 * hi;
                if (kvrel > l31) sa[r] = -1e30f;
            }
        }
        float pm = sa[0];
        #pragma unroll
        for (int r = 1; r < 16; ++r) pm = fmaxf(pm, sa[r]);
        pm = fmaxf(pm, __shfl_xor(pm, 32));
        if (!__all(pm <= m + 8.f)) {   // deferred rescale (THR=8, log2 domain)
            float mn = fmaxf(m, pm);
            float corr = exp2f(m - mn);
            s *= corr;
            #pragma unroll
            for (int r = 0; r < 16; ++r) { o0[r] *= corr; o1[r] *= corr; }
            m = mn;
        }
        float p[16]; float rs = 0.f;
        #pragma unroll
        for (int r = 0; r < 16; ++r) { p[r] = exp2f(sa[r] - m); rs += p[r]; }
        rs += __shfl_xor(rs, 32);
        s += rs;
        // pack P -> bf16 PV B-fragments (lane pair l <-> l^32 exchange)
        unsigned pk[8];
        #pragma unroll
        for (int jj = 0; jj < 8; ++jj) pk[jj] = pkbf(p[2 * jj], p[2 * jj + 1]);
        unsigned pks[8];
        #pragma unroll
        for (int jj = 0; jj < 8; ++jj) pks[jj] = (unsigned)__shfl_xor((int)pk[jj], 32);
        U8u pa0, pa1;
        pa0.u[0] = hi ? pks[2] : pk[0];
        pa0.u[1] = hi ? pks[3] : pk[1];
        pa0.u[2] = hi ? pk[2]  : pks[0];
        pa0.u[3] = hi ? pk[3]  : pks[1];
        pa1.u[0] = hi ? pks[6] : pk[4];
        pa1.u[1] = hi ? pks[7] : pk[5];
        pa1.u[2] = hi ? pk[6]  : pks[4];
        pa1.u[3] = hi ? pk[7]  : pks[5];
        // O^T[d][q] += V^T[d][kv] * P[kv][q]  (this wave's 2 d-blocks)
        const __hip_bfloat16* vpt = vp + kvb + hi * 8;
        __builtin_amdgcn_s_setprio(1);
        {
            bf16x8 vf0 = *(const bf16x8*)(vpt);
            bf16x8 vf1 = *(const bf16x8*)(vpt + 16);
            o0 = __builtin_amdgcn_mfma_f32_32x32x16_bf16(vf0, pa0.v, o0, 0, 0, 0);
            o0 = __builtin_amdgcn_mfma_f32_32x32x16_bf16(vf1, pa1.v, o0, 0, 0, 0);
        }
        {
            bf16x8 vf0 = *(const bf16x8*)(vpt + (size_t)32 * T_);
            bf16x8 vf1 = *(const bf16x8*)(vpt + (size_t)32 * T_ + 16);
            o1 = __builtin_amdgcn_mfma_f32_32x32x16_bf16(vf0, pa0.v, o1, 0, 0, 0);
            o1 = __builtin_amdgcn_mfma_f32_32x32x16_bf16(vf1, pa1.v, o1, 0, 0, 0);
        }
        __builtin_amdgcn_s_setprio(0);
    }

    // ---- cross-segment merge (tree): segs {1,3} -> {0,2}, then 2 -> 0 ----
    auto writePart = [&](int buf) {
        #pragma unroll
        for (int r = 0; r < 16; ++r) {
            lO[dh][buf][r * 64 + lane]        = o0[r];
            lO[dh][buf][(r + 16) * 64 + lane] = o1[r];
        }
        if (dh == 0) { lms[buf][0][lane] = m; lms[buf][1][lane] = s; }
    };
    auto mergePart = [&](int buf) {
        float mp = lms[buf][0][lane], sp = lms[buf][1][lane];
        float mn = fmaxf(m, mp);
        float ca = exp2f(m - mn), cb = exp2f(mp - mn);
        s = s * ca + sp * cb;
        #pragma unroll
        for (int r = 0; r < 16; ++r) {
            o0[r] = o0[r] * ca + lO[dh][buf][r * 64 + lane] * cb;
            o1[r] = o1[r] * ca + lO[dh][buf][(r + 16) * 64 + lane] * cb;
        }
        m = mn;
    };

    if (seg == 1) writePart(0);
    if (seg == 3) writePart(1);
    __syncthreads();
    if (seg == 0) mergePart(0);
    if (seg == 2) mergePart(1);
    __syncthreads();
    if (seg == 2) writePart(0);
    __syncthreads();
    if (seg == 0) {
        mergePart(0);
        float inv = 1.0f / s;
        __hip_bfloat16* yrow = yb + ((size_t)b * T_ + qa + l31) * D_ + h * HD_;
        #define WRITE_DB(ON, DB)                                                        \
            _Pragma("unroll")                                                           \
            for (int r4 = 0; r4 < 4; ++r4) {                                            \
                ushort4 u;                                                              \
                __hip_bfloat16 e0 = __float2bfloat16(ON[4*r4+0] * inv);                 \
                __hip_bfloat16 e1 = __float2bfloat16(ON[4*r4+1] * inv);                 \
                __hip_bfloat16 e2 = __float2bfloat16(ON[4*r4+2] * inv);                 \
                __hip_bfloat16 e3 = __float2bfloat16(ON[4*r4+3] * inv);                 \
                u.x = *(const unsigned short*)&e0; u.y = *(const unsigned short*)&e1;   \
                u.z = *(const unsigned short*)&e2; u.w = *(const unsigned short*)&e3;   \
                *(ushort4*)(yrow + (DB) * 32 + 8 * r4 + 4 * hi) = u;                    \
            }
        WRITE_DB(o0, dh * 2 + 0)
        WRITE_DB(o1, dh * 2 + 1)
        #undef WRITE_DB
    }
}

extern "C" void kernel_launch(void* const* d_in, const int* in_sizes, int n_in,
                              void* d_out, int out_size, void* d_ws, size_t ws_size,
                              hipStream_t stream) {
    (void)in_sizes; (void)n_in; (void)out_size; (void)ws_size;
    const float* x  = (const float*)d_in[0];
    const float* wq = (const float*)d_in[1];
    const float* wk = (const float*)d_in[2];
    const float* wv = (const float*)d_in[3];
    const float* wp = (const float*)d_in[4];
    const float* qg = (const float*)d_in[5];
    float* out = (float*)d_out;

    char* ws = (char*)d_ws;
    size_t off = 0;
    auto alloc = [&](size_t bytes) { char* p = ws + off; off += (bytes + 255) & ~(size_t)255; return p; };

    __hip_bfloat16* xb  = (__hip_bfloat16*)alloc((size_t)BT_ * D_ * 2);
    __hip_bfloat16* wqb = (__hip_bfloat16*)alloc((size_t)D_ * D_ * 2);
    __hip_bfloat16* wkb = (__hip_bfloat16*)alloc((size_t)KD_ * D_ * 2);
    __hip_bfloat16* wvb = (__hip_bfloat16*)alloc((size_t)KD_ * D_ * 2);
    __hip_bfloat16* wpb = (__hip_bfloat16*)alloc((size_t)D_ * D_ * 2);
    float* qf = (float*)alloc((size_t)BT_ * D_ * 4);
    float* kf = (float*)alloc((size_t)BT_ * KD_ * 4);
    float* vf = (float*)alloc((size_t)BT_ * KD_ * 4);
    __hip_bfloat16* qbb = (__hip_bfloat16*)alloc((size_t)BT_ * D_ * 2);
    __hip_bfloat16* kbb = (__hip_bfloat16*)alloc((size_t)BT_ * KD_ * 2);
    // aliases (lifetimes disjoint on the sequential stream):
    __hip_bfloat16* ybb = xb;                   // yb written after xb's last read
    __hip_bfloat16* vbb = wqb;                  // wqb dead after q-projection
    __hip_bfloat16* vtb = wqb + (size_t)B_ * NKV_ * T_ * HD_;

    f2b_kernel<<<2048, 256, 0, stream>>>((const float4*)x,  (ushort4*)xb,  BT_ * D_ / 4);
    f2b_kernel<<<2048, 256, 0, stream>>>((const float4*)wq, (ushort4*)wqb, D_ * D_ / 4);
    f2b_kernel<<<2048, 256, 0, stream>>>((const float4*)wk, (ushort4*)wkb, KD_ * D_ / 4);
    f2b_kernel<<<2048, 256, 0, stream>>>((const float4*)wv, (ushort4*)wvb, KD_ * D_ / 4);
    f2b_kernel<<<2048, 256, 0, stream>>>((const float4*)wp, (ushort4*)wpb, D_ * D_ / 4);

    dim3 gq(BT_ / 128, D_ / 128);
    gemm_bt<<<gq, 256, 0, stream>>>(xb, wqb, qf, BT_, D_, D_);
    dim3 gkv(BT_ / 128, KD_ / 128);
    gemm_bt<<<gkv, 256, 0, stream>>>(xb, wkb, kf, BT_, KD_, D_);
    gemm_bt<<<gkv, 256, 0, stream>>>(xb, wvb, vf, BT_, KD_, D_);

    norm_rope<<<(BT_ * 24) / 4, 256, 0, stream>>>(qf, kf, vf, qg, qbb, kbb, vbb);

    dim3 gt(T_ / 32, HD_ / 32, B_ * NKV_);
    vtrans<<<gt, dim3(32, 8), 0, stream>>>(vbb, vtb);

    attn_fwd<<<2048, 512, 0, stream>>>(qbb, kbb, vtb, ybb);

    gemm_bt<<<gq, 256, 0, stream>>>(ybb, wpb, out, BT_, D_, D_);
}

// Round 5
// 351.623 us; speedup vs baseline: 1.2663x; 1.2663x over previous
//
#include <hip/hip_runtime.h>
#include <hip/hip_bf16.h>

#define B_   2
#define T_   2048
#define D_   2048
#define NH_  16
#define NKV_ 4
#define HD_  128
#define KD_  512   // NKV*HD
#define BT_  4096  // B_*T_

typedef __bf16 bf16x8 __attribute__((ext_vector_type(8)));
typedef float  f32x4  __attribute__((ext_vector_type(4)));
typedef float  f32x16 __attribute__((ext_vector_type(16)));

__device__ __forceinline__ void gload_lds16(const __hip_bfloat16* g, __hip_bfloat16* l) {
    __builtin_amdgcn_global_load_lds(
        (__attribute__((address_space(1))) void*)(g),
        (__attribute__((address_space(3))) void*)(l),
        16, 0, 0);
}

// ---------------- fp32 -> bf16 convert ----------------
__global__ void f2b_kernel(const float4* __restrict__ in, ushort4* __restrict__ out, int n4) {
    int idx = blockIdx.x * blockDim.x + threadIdx.x;
    int stride = gridDim.x * blockDim.x;
    for (int j = idx; j < n4; j += stride) {
        float4 v = in[j];
        __hip_bfloat16 a = __float2bfloat16(v.x), b = __float2bfloat16(v.y),
                       c = __float2bfloat16(v.z), d = __float2bfloat16(v.w);
        ushort4 o;
        o.x = *(const unsigned short*)&a; o.y = *(const unsigned short*)&b;
        o.z = *(const unsigned short*)&c; o.w = *(const unsigned short*)&d;
        out[j] = o;
    }
}

// ---------------- GEMM: C(MxN) = A(MxK) * B(NxK)^T, bf16 in, f32 out ----------------
__global__ __launch_bounds__(256)
void gemm_bt(const __hip_bfloat16* __restrict__ A, const __hip_bfloat16* __restrict__ B,
             float* __restrict__ C, int M, int N, int K) {
    __shared__ __attribute__((aligned(16))) __hip_bfloat16 As[128 * 32];
    __shared__ __attribute__((aligned(16))) __hip_bfloat16 Bs[128 * 32];
    const int tid  = threadIdx.x;
    const int w    = tid >> 6;
    const int lane = tid & 63;
    const int lr   = lane & 15;
    const int lk   = lane >> 4;
    const int wr   = w >> 1, wc = w & 1;
    const size_t row0 = (size_t)blockIdx.x * 128;
    const size_t col0 = (size_t)blockIdx.y * 128;

    const __hip_bfloat16* ga = A + (row0 + tid / 4) * K + (tid % 4) * 8;
    const __hip_bfloat16* gb = B + (col0 + tid / 4) * K + (tid % 4) * 8;
    __hip_bfloat16* lA0 = &As[w * 512];
    __hip_bfloat16* lA1 = &As[2048 + w * 512];
    __hip_bfloat16* lB0 = &Bs[w * 512];
    __hip_bfloat16* lB1 = &Bs[2048 + w * 512];

    f32x4 acc[4][4] = {};
    for (int k0 = 0; k0 < K; k0 += 32) {
        gload_lds16(ga + k0,                 lA0);
        gload_lds16(ga + k0 + (size_t)64*K,  lA1);
        gload_lds16(gb + k0,                 lB0);
        gload_lds16(gb + k0 + (size_t)64*K,  lB1);
        __syncthreads();
        bf16x8 af[4], bfr[4];
        #pragma unroll
        for (int m = 0; m < 4; m++)
            af[m] = *(const bf16x8*)&As[(wr * 64 + m * 16 + lr) * 32 + lk * 8];
        #pragma unroll
        for (int n = 0; n < 4; n++)
            bfr[n] = *(const bf16x8*)&Bs[(wc * 64 + n * 16 + lr) * 32 + lk * 8];
        #pragma unroll
        for (int m = 0; m < 4; m++)
            #pragma unroll
            for (int n = 0; n < 4; n++)
                acc[m][n] = __builtin_amdgcn_mfma_f32_16x16x32_bf16(af[m], bfr[n], acc[m][n], 0, 0, 0);
        __syncthreads();
    }
    #pragma unroll
    for (int m = 0; m < 4; m++)
        #pragma unroll
        for (int n = 0; n < 4; n++)
            #pragma unroll
            for (int r = 0; r < 4; r++)
                C[(row0 + wr * 64 + m * 16 + lk * 4 + r) * N + col0 + wc * 64 + n * 16 + lr] = acc[m][n][r];
}

// ---------------- RMSNorm + partial RoPE + gain; v passthrough to bf16 ----------------
__global__ __launch_bounds__(256)
void norm_rope(const float* __restrict__ qf, const float* __restrict__ kf, const float* __restrict__ vf,
               const float* __restrict__ qg,
               __hip_bfloat16* __restrict__ qb, __hip_bfloat16* __restrict__ kb, __hip_bfloat16* __restrict__ vb) {
    int wid  = (blockIdx.x * 256 + threadIdx.x) >> 6;
    int lane = threadIdx.x & 63;
    int bt = wid / 24, hh = wid % 24;
    int b = bt >> 11, t = bt & (T_ - 1);

    const float* row;
    if (hh < NH_)            row = qf + (size_t)bt * D_  + hh * HD_;
    else if (hh < NH_+NKV_)  row = kf + (size_t)bt * KD_ + (hh - NH_) * HD_;
    else                     row = vf + (size_t)bt * KD_ + (hh - NH_ - NKV_) * HD_;

    float2 xv = *(const float2*)(row + lane * 2);

    if (hh >= NH_ + NKV_) {  // v: just convert
        int kv = hh - NH_ - NKV_;
        __hip_bfloat16* o = vb + ((size_t)(b * NKV_ + kv) * T_ + t) * HD_ + lane * 2;
        o[0] = __float2bfloat16(xv.x); o[1] = __float2bfloat16(xv.y);
        return;
    }

    float ss = xv.x * xv.x + xv.y * xv.y;
    #pragma unroll
    for (int off = 32; off; off >>= 1) ss += __shfl_xor(ss, off);
    float rn = rsqrtf(ss * (1.0f / HD_) + 1.1920929e-7f);
    float y0 = xv.x * rn, y1 = xv.y * rn;

    float py0 = __shfl_xor(y0, 4), py1 = __shfl_xor(y1, 4);
    float o0 = y0, o1 = y1;
    if (lane < 8) {
        int i0 = (2 * lane) & 7;
        float f0 = (float)t * exp2f(-(float)i0       * 1.66096404744368f);
        float f1 = (float)t * exp2f(-(float)(i0 + 1) * 1.66096404744368f);
        float s0, c0, s1, c1;
        sincosf(f0, &s0, &c0);
        sincosf(f1, &s1, &c1);
        if (lane < 4) { o0 =  y0 * c0 + py0 * s0; o1 =  y1 * c1 + py1 * s1; }
        else          { o0 = -y0 * c0 + py0 * s0; o1 = -y1 * c1 + py1 * s1; }
    }

    if (hh < NH_) {
        // fold gain * 1/sqrt(HD) * log2(e) into q
        float g = qg[hh] * 0.1275174305f;
        o0 *= g; o1 *= g;
        __hip_bfloat16* o = qb + ((size_t)(b * NH_ + hh) * T_ + t) * HD_ + lane * 2;
        o[0] = __float2bfloat16(o0); o[1] = __float2bfloat16(o1);
    } else {
        int kv = hh - NH_;
        __hip_bfloat16* o = kb + ((size_t)(b * NKV_ + kv) * T_ + t) * HD_ + lane * 2;
        o[0] = __float2bfloat16(o0); o[1] = __float2bfloat16(o1);
    }
}

// ---------------- V transpose: [bk][T][HD] -> [bk][HD][T] ----------------
__global__ void vtrans(const __hip_bfloat16* __restrict__ vb, __hip_bfloat16* __restrict__ vt) {
    __shared__ __hip_bfloat16 tile[32][33];
    int bk = blockIdx.z;
    int t0 = blockIdx.x * 32, h0 = blockIdx.y * 32;
    int tx = threadIdx.x, ty = threadIdx.y;  // 32 x 8
    const __hip_bfloat16* src = vb + ((size_t)bk * T_ + t0) * HD_ + h0;
    #pragma unroll
    for (int j = 0; j < 4; j++) tile[ty + j * 8][tx] = src[(size_t)(ty + j * 8) * HD_ + tx];
    __syncthreads();
    __hip_bfloat16* dst = vt + ((size_t)bk * HD_ + h0) * T_ + t0;
    #pragma unroll
    for (int j = 0; j < 4; j++) dst[(size_t)(ty + j * 8) * T_ + tx] = tile[tx][ty + j * 8];
}

// ---------------- causal GQA flash attention ----------------
// Block = 4 waves = 4 GQA q-heads of one (b, kv-head, 32-row q-chunk).
// K/V tiles (32 kv rows) staged in LDS via global_load_lds, double-buffered,
// shared by all 4 waves. Swapped-QK 32x32 MFMA, in-register online softmax.
// LDS layouts (16B-chunk indexed, conflict-free read AND linear write):
//   K: chunk u = hslot*32 + kv   (hslot 0..15 covers h = hslot*8..+8)
//   V: chunk u = kvg*128 + d     (kvg 0..3 covers kv = kvg*8..+8; V^T rows d)
__device__ __forceinline__ unsigned pkbf(float a, float b) {
    __hip_bfloat16 x = __float2bfloat16(a), y = __float2bfloat16(b);
    unsigned short xu = *(const unsigned short*)&x, yu = *(const unsigned short*)&y;
    return (unsigned)xu | ((unsigned)yu << 16);
}

union U8u { unsigned u[4]; bf16x8 v; };

__global__ __launch_bounds__(256, 2)
void attn_fwd(const __hip_bfloat16* __restrict__ qb, const __hip_bfloat16* __restrict__ kb,
              const __hip_bfloat16* __restrict__ vt, __hip_bfloat16* __restrict__ yb) {
    __shared__ __attribute__((aligned(16))) __hip_bfloat16 Ks[2][4096];  // 8KB per buf
    __shared__ __attribute__((aligned(16))) __hip_bfloat16 Vs[2][4096];  // 8KB per buf
    const int tid  = threadIdx.x;
    const int w    = tid >> 6, lane = tid & 63;
    const int l31  = lane & 31, hi = lane >> 5;
    const int bid  = blockIdx.x;
    const int strm = bid & 7;              // = b*4 + kvh; consecutive bids -> different XCDs,
    const int b    = strm >> 2, kvh = strm & 3;  // same-XCD blocks share one K/V stream in L2
    const int c    = 63 - (bid >> 3);      // LPT: longest chunks dispatched first
    const int h    = kvh * 4 + w;          // wave = GQA head
    const int qa   = c * 32;

    const __hip_bfloat16* qp = qb + ((size_t)(b * NH_ + h) * T_ + qa) * HD_;
    const __hip_bfloat16* kp = kb + (size_t)(b * NKV_ + kvh) * T_ * HD_;
    const __hip_bfloat16* vp = vt + (size_t)(b * NKV_ + kvh) * HD_ * T_;

    // per-thread staging source coordinates (constant across tiles)
    const int k_hs = tid >> 5, k_kv = tid & 31;       // K chunk u = tid
    const int v_kg = tid >> 7, v_d  = tid & 127;      // V chunk u = tid
    const __hip_bfloat16* ksrc0 = kp + (size_t)k_kv * HD_ + k_hs * 8;
    const __hip_bfloat16* ksrc1 = kp + (size_t)k_kv * HD_ + (8 + k_hs) * 8;
    const __hip_bfloat16* vsrc0 = vp + (size_t)v_d * T_ + v_kg * 8;
    const __hip_bfloat16* vsrc1 = vp + (size_t)v_d * T_ + (2 + v_kg) * 8;

    auto stage = [&](int kt, int bf) {
        const int kvb = kt * 32;
        __hip_bfloat16* kd = &Ks[bf][w * 512];
        __hip_bfloat16* vd = &Vs[bf][w * 512];
        gload_lds16(ksrc0 + (size_t)kvb * HD_, kd);
        gload_lds16(ksrc1 + (size_t)kvb * HD_, kd + 2048);
        gload_lds16(vsrc0 + kvb,               vd);
        gload_lds16(vsrc1 + kvb,               vd + 2048);
    };

    bf16x8 qfr[8];
    #pragma unroll
    for (int hb = 0; hb < 8; ++hb)
        qfr[hb] = *(const bf16x8*)(qp + (size_t)l31 * HD_ + hb * 16 + hi * 8);

    f32x16 o0 = {}, o1 = {}, o2 = {}, o3 = {};
    float m = -1e30f, s = 0.f;

    stage(0, 0);
    __syncthreads();   // compiler drains vmcnt before s_barrier

    for (int kt = 0; kt <= c; ++kt) {
        const int cur = kt & 1;
        if (kt < c) stage(kt + 1, cur ^ 1);

        const __hip_bfloat16* Kb = &Ks[cur][0];
        const __hip_bfloat16* Vb = &Vs[cur][0];

        // S^T[kv][q] = sum_hd K[kv][hd] * Q[q][hd]  (two independent 4-chains)
        f32x16 sa_a = {}, sa_b = {};
        __builtin_amdgcn_s_setprio(1);
        #pragma unroll
        for (int hb = 0; hb < 4; ++hb) {
            bf16x8 kf = *(const bf16x8*)&Kb[((hb * 2 + hi) * 32 + l31) * 8];
            sa_a = __builtin_amdgcn_mfma_f32_32x32x16_bf16(kf, qfr[hb], sa_a, 0, 0, 0);
        }
        #pragma unroll
        for (int hb = 4; hb < 8; ++hb) {
            bf16x8 kf = *(const bf16x8*)&Kb[((hb * 2 + hi) * 32 + l31) * 8];
            sa_b = __builtin_amdgcn_mfma_f32_32x32x16_bf16(kf, qfr[hb], sa_b, 0, 0, 0);
        }
        __builtin_amdgcn_s_setprio(0);
        f32x16 sa = sa_a + sa_b;

        if (kt == c) {  // diagonal tile: mask kv > q (relative indices)
            #pragma unroll
            for (int r = 0; r < 16; ++r) {
                int kvrel = (r & 3) + 8 * (r >> 2) + 4 * hi;
                if (kvrel > l31) sa[r] = -1e30f;
            }
        }
        float pm = sa[0];
        #pragma unroll
        for (int r = 1; r < 16; ++r) pm = fmaxf(pm, sa[r]);
        pm = fmaxf(pm, __shfl_xor(pm, 32));
        if (!__all(pm <= m + 8.f)) {   // deferred rescale (THR=8, log2 domain)
            float mn = fmaxf(m, pm);
            float corr = exp2f(m - mn);
            s *= corr;
            #pragma unroll
            for (int r = 0; r < 16; ++r) { o0[r] *= corr; o1[r] *= corr; o2[r] *= corr; o3[r] *= corr; }
            m = mn;
        }
        float p[16]; float rs = 0.f;
        #pragma unroll
        for (int r = 0; r < 16; ++r) { p[r] = exp2f(sa[r] - m); rs += p[r]; }
        rs += __shfl_xor(rs, 32);
        s += rs;
        // pack P -> bf16 PV B-fragments (lane pair l <-> l^32 exchange)
        unsigned pk[8];
        #pragma unroll
        for (int jj = 0; jj < 8; ++jj) pk[jj] = pkbf(p[2 * jj], p[2 * jj + 1]);
        unsigned pks[8];
        #pragma unroll
        for (int jj = 0; jj < 8; ++jj) pks[jj] = (unsigned)__shfl_xor((int)pk[jj], 32);
        U8u pa0, pa1;
        pa0.u[0] = hi ? pks[2] : pk[0];
        pa0.u[1] = hi ? pks[3] : pk[1];
        pa0.u[2] = hi ? pk[2]  : pks[0];
        pa0.u[3] = hi ? pk[3]  : pks[1];
        pa1.u[0] = hi ? pks[6] : pk[4];
        pa1.u[1] = hi ? pks[7] : pk[5];
        pa1.u[2] = hi ? pk[6]  : pks[4];
        pa1.u[3] = hi ? pk[7]  : pks[5];
        // O^T[d][q] += V^T[d][kv] * P[kv][q]
        __builtin_amdgcn_s_setprio(1);
        #define PV_BLK(ON, DBLK)                                                              \
            {                                                                                 \
                bf16x8 vf0 = *(const bf16x8*)&Vb[((0 + hi) * 128 + (DBLK) * 32 + l31) * 8];   \
                bf16x8 vf1 = *(const bf16x8*)&Vb[((2 + hi) * 128 + (DBLK) * 32 + l31) * 8];   \
                ON = __builtin_amdgcn_mfma_f32_32x32x16_bf16(vf0, pa0.v, ON, 0, 0, 0);        \
                ON = __builtin_amdgcn_mfma_f32_32x32x16_bf16(vf1, pa1.v, ON, 0, 0, 0);        \
            }
        PV_BLK(o0, 0) PV_BLK(o1, 1) PV_BLK(o2, 2) PV_BLK(o3, 3)
        #undef PV_BLK
        __builtin_amdgcn_s_setprio(0);

        __syncthreads();   // drains staging DMA + LDS reads before buffer swap
    }

    float inv = 1.0f / s;
    __hip_bfloat16* yrow = yb + ((size_t)b * T_ + qa + l31) * D_ + h * HD_;
    #define WRITE_DB(ON, DB)                                                        \
        _Pragma("unroll")                                                           \
        for (int r4 = 0; r4 < 4; ++r4) {                                            \
            ushort4 u;                                                              \
            __hip_bfloat16 e0 = __float2bfloat16(ON[4*r4+0] * inv);                 \
            __hip_bfloat16 e1 = __float2bfloat16(ON[4*r4+1] * inv);                 \
            __hip_bfloat16 e2 = __float2bfloat16(ON[4*r4+2] * inv);                 \
            __hip_bfloat16 e3 = __float2bfloat16(ON[4*r4+3] * inv);                 \
            u.x = *(const unsigned short*)&e0; u.y = *(const unsigned short*)&e1;   \
            u.z = *(const unsigned short*)&e2; u.w = *(const unsigned short*)&e3;   \
            *(ushort4*)(yrow + (DB) * 32 + 8 * r4 + 4 * hi) = u;                    \
        }
    WRITE_DB(o0, 0) WRITE_DB(o1, 1) WRITE_DB(o2, 2) WRITE_DB(o3, 3)
    #undef WRITE_DB
}

extern "C" void kernel_launch(void* const* d_in, const int* in_sizes, int n_in,
                              void* d_out, int out_size, void* d_ws, size_t ws_size,
                              hipStream_t stream) {
    (void)in_sizes; (void)n_in; (void)out_size; (void)ws_size;
    const float* x  = (const float*)d_in[0];
    const float* wq = (const float*)d_in[1];
    const float* wk = (const float*)d_in[2];
    const float* wv = (const float*)d_in[3];
    const float* wp = (const float*)d_in[4];
    const float* qg = (const float*)d_in[5];
    float* out = (float*)d_out;

    char* ws = (char*)d_ws;
    size_t off = 0;
    auto alloc = [&](size_t bytes) { char* p = ws + off; off += (bytes + 255) & ~(size_t)255; return p; };

    __hip_bfloat16* xb  = (__hip_bfloat16*)alloc((size_t)BT_ * D_ * 2);
    __hip_bfloat16* wqb = (__hip_bfloat16*)alloc((size_t)D_ * D_ * 2);
    __hip_bfloat16* wkb = (__hip_bfloat16*)alloc((size_t)KD_ * D_ * 2);
    __hip_bfloat16* wvb = (__hip_bfloat16*)alloc((size_t)KD_ * D_ * 2);
    __hip_bfloat16* wpb = (__hip_bfloat16*)alloc((size_t)D_ * D_ * 2);
    float* qf = (float*)alloc((size_t)BT_ * D_ * 4);
    float* kf = (float*)alloc((size_t)BT_ * KD_ * 4);
    float* vf = (float*)alloc((size_t)BT_ * KD_ * 4);
    __hip_bfloat16* qbb = (__hip_bfloat16*)alloc((size_t)BT_ * D_ * 2);
    __hip_bfloat16* kbb = (__hip_bfloat16*)alloc((size_t)BT_ * KD_ * 2);
    // aliases (lifetimes disjoint on the sequential stream):
    __hip_bfloat16* ybb = xb;                   // yb written after xb's last read
    __hip_bfloat16* vbb = wqb;                  // wqb dead after q-projection
    __hip_bfloat16* vtb = wqb + (size_t)B_ * NKV_ * T_ * HD_;

    f2b_kernel<<<2048, 256, 0, stream>>>((const float4*)x,  (ushort4*)xb,  BT_ * D_ / 4);
    f2b_kernel<<<2048, 256, 0, stream>>>((const float4*)wq, (ushort4*)wqb, D_ * D_ / 4);
    f2b_kernel<<<2048, 256, 0, stream>>>((const float4*)wk, (ushort4*)wkb, KD_ * D_ / 4);
    f2b_kernel<<<2048, 256, 0, stream>>>((const float4*)wv, (ushort4*)wvb, KD_ * D_ / 4);
    f2b_kernel<<<2048, 256, 0, stream>>>((const float4*)wp, (ushort4*)wpb, D_ * D_ / 4);

    dim3 gq(BT_ / 128, D_ / 128);
    gemm_bt<<<gq, 256, 0, stream>>>(xb, wqb, qf, BT_, D_, D_);
    dim3 gkv(BT_ / 128, KD_ / 128);
    gemm_bt<<<gkv, 256, 0, stream>>>(xb, wkb, kf, BT_, KD_, D_);
    gemm_bt<<<gkv, 256, 0, stream>>>(xb, wvb, vf, BT_, KD_, D_);

    norm_rope<<<(BT_ * 24) / 4, 256, 0, stream>>>(qf, kf, vf, qg, qbb, kbb, vbb);

    dim3 gt(T_ / 32, HD_ / 32, B_ * NKV_);
    vtrans<<<gt, dim3(32, 8), 0, stream>>>(vbb, vtb);

    attn_fwd<<<512, 256, 0, stream>>>(qbb, kbb, vtb, ybb);

    gemm_bt<<<gq, 256, 0, stream>>>(ybb, wpb, out, BT_, D_, D_);
}

// Round 6
// 333.422 us; speedup vs baseline: 1.3355x; 1.0546x over previous
//
#include <hip/hip_runtime.h>
#include <hip/hip_bf16.h>

#define B_   2
#define T_   2048
#define D_   2048
#define NH_  16
#define NKV_ 4
#define HD_  128
#define KD_  512   // NKV*HD
#define BT_  4096  // B_*T_

typedef __bf16 bf16x8 __attribute__((ext_vector_type(8)));
typedef float  f32x4  __attribute__((ext_vector_type(4)));
typedef float  f32x16 __attribute__((ext_vector_type(16)));

__device__ __forceinline__ void gload_lds16(const __hip_bfloat16* g, __hip_bfloat16* l) {
    __builtin_amdgcn_global_load_lds(
        (__attribute__((address_space(1))) void*)(g),
        (__attribute__((address_space(3))) void*)(l),
        16, 0, 0);
}

// ---------------- fp32 -> bf16 convert ----------------
__global__ void f2b_kernel(const float4* __restrict__ in, ushort4* __restrict__ out, int n4) {
    int idx = blockIdx.x * blockDim.x + threadIdx.x;
    int stride = gridDim.x * blockDim.x;
    for (int j = idx; j < n4; j += stride) {
        float4 v = in[j];
        __hip_bfloat16 a = __float2bfloat16(v.x), b = __float2bfloat16(v.y),
                       c = __float2bfloat16(v.z), d = __float2bfloat16(v.w);
        ushort4 o;
        o.x = *(const unsigned short*)&a; o.y = *(const unsigned short*)&b;
        o.z = *(const unsigned short*)&c; o.w = *(const unsigned short*)&d;
        out[j] = o;
    }
}

// ---------------- GEMM: C(MxN) = A(MxK) * B(NxK)^T, bf16 in, f32 out ----------------
__global__ __launch_bounds__(256)
void gemm_bt(const __hip_bfloat16* __restrict__ A, const __hip_bfloat16* __restrict__ B,
             float* __restrict__ C, int M, int N, int K) {
    __shared__ __attribute__((aligned(16))) __hip_bfloat16 As[128 * 32];
    __shared__ __attribute__((aligned(16))) __hip_bfloat16 Bs[128 * 32];
    const int tid  = threadIdx.x;
    const int w    = tid >> 6;
    const int lane = tid & 63;
    const int lr   = lane & 15;
    const int lk   = lane >> 4;
    const int wr   = w >> 1, wc = w & 1;
    const size_t row0 = (size_t)blockIdx.x * 128;
    const size_t col0 = (size_t)blockIdx.y * 128;

    const __hip_bfloat16* ga = A + (row0 + tid / 4) * K + (tid % 4) * 8;
    const __hip_bfloat16* gb = B + (col0 + tid / 4) * K + (tid % 4) * 8;
    __hip_bfloat16* lA0 = &As[w * 512];
    __hip_bfloat16* lA1 = &As[2048 + w * 512];
    __hip_bfloat16* lB0 = &Bs[w * 512];
    __hip_bfloat16* lB1 = &Bs[2048 + w * 512];

    f32x4 acc[4][4] = {};
    for (int k0 = 0; k0 < K; k0 += 32) {
        gload_lds16(ga + k0,                 lA0);
        gload_lds16(ga + k0 + (size_t)64*K,  lA1);
        gload_lds16(gb + k0,                 lB0);
        gload_lds16(gb + k0 + (size_t)64*K,  lB1);
        __syncthreads();
        bf16x8 af[4], bfr[4];
        #pragma unroll
        for (int m = 0; m < 4; m++)
            af[m] = *(const bf16x8*)&As[(wr * 64 + m * 16 + lr) * 32 + lk * 8];
        #pragma unroll
        for (int n = 0; n < 4; n++)
            bfr[n] = *(const bf16x8*)&Bs[(wc * 64 + n * 16 + lr) * 32 + lk * 8];
        #pragma unroll
        for (int m = 0; m < 4; m++)
            #pragma unroll
            for (int n = 0; n < 4; n++)
                acc[m][n] = __builtin_amdgcn_mfma_f32_16x16x32_bf16(af[m], bfr[n], acc[m][n], 0, 0, 0);
        __syncthreads();
    }
    #pragma unroll
    for (int m = 0; m < 4; m++)
        #pragma unroll
        for (int n = 0; n < 4; n++)
            #pragma unroll
            for (int r = 0; r < 4; r++)
                C[(row0 + wr * 64 + m * 16 + lk * 4 + r) * N + col0 + wc * 64 + n * 16 + lr] = acc[m][n][r];
}

// ---------------- RMSNorm + partial RoPE + gain; v passthrough to bf16 ----------------
__global__ __launch_bounds__(256)
void norm_rope(const float* __restrict__ qf, const float* __restrict__ kf, const float* __restrict__ vf,
               const float* __restrict__ qg,
               __hip_bfloat16* __restrict__ qb, __hip_bfloat16* __restrict__ kb, __hip_bfloat16* __restrict__ vb) {
    int wid  = (blockIdx.x * 256 + threadIdx.x) >> 6;
    int lane = threadIdx.x & 63;
    int bt = wid / 24, hh = wid % 24;
    int b = bt >> 11, t = bt & (T_ - 1);

    const float* row;
    if (hh < NH_)            row = qf + (size_t)bt * D_  + hh * HD_;
    else if (hh < NH_+NKV_)  row = kf + (size_t)bt * KD_ + (hh - NH_) * HD_;
    else                     row = vf + (size_t)bt * KD_ + (hh - NH_ - NKV_) * HD_;

    float2 xv = *(const float2*)(row + lane * 2);

    if (hh >= NH_ + NKV_) {  // v: just convert
        int kv = hh - NH_ - NKV_;
        __hip_bfloat16* o = vb + ((size_t)(b * NKV_ + kv) * T_ + t) * HD_ + lane * 2;
        o[0] = __float2bfloat16(xv.x); o[1] = __float2bfloat16(xv.y);
        return;
    }

    float ss = xv.x * xv.x + xv.y * xv.y;
    #pragma unroll
    for (int off = 32; off; off >>= 1) ss += __shfl_xor(ss, off);
    float rn = rsqrtf(ss * (1.0f / HD_) + 1.1920929e-7f);
    float y0 = xv.x * rn, y1 = xv.y * rn;

    float py0 = __shfl_xor(y0, 4), py1 = __shfl_xor(y1, 4);
    float o0 = y0, o1 = y1;
    if (lane < 8) {
        int i0 = (2 * lane) & 7;
        float f0 = (float)t * exp2f(-(float)i0       * 1.66096404744368f);
        float f1 = (float)t * exp2f(-(float)(i0 + 1) * 1.66096404744368f);
        float s0, c0, s1, c1;
        sincosf(f0, &s0, &c0);
        sincosf(f1, &s1, &c1);
        if (lane < 4) { o0 =  y0 * c0 + py0 * s0; o1 =  y1 * c1 + py1 * s1; }
        else          { o0 = -y0 * c0 + py0 * s0; o1 = -y1 * c1 + py1 * s1; }
    }

    if (hh < NH_) {
        // fold gain * 1/sqrt(HD) * log2(e) into q
        float g = qg[hh] * 0.1275174305f;
        o0 *= g; o1 *= g;
        __hip_bfloat16* o = qb + ((size_t)(b * NH_ + hh) * T_ + t) * HD_ + lane * 2;
        o[0] = __float2bfloat16(o0); o[1] = __float2bfloat16(o1);
    } else {
        int kv = hh - NH_;
        __hip_bfloat16* o = kb + ((size_t)(b * NKV_ + kv) * T_ + t) * HD_ + lane * 2;
        o[0] = __float2bfloat16(o0); o[1] = __float2bfloat16(o1);
    }
}

// ---------------- V transpose: [bk][T][HD] -> [bk][HD][T] ----------------
__global__ void vtrans(const __hip_bfloat16* __restrict__ vb, __hip_bfloat16* __restrict__ vt) {
    __shared__ __hip_bfloat16 tile[32][33];
    int bk = blockIdx.z;
    int t0 = blockIdx.x * 32, h0 = blockIdx.y * 32;
    int tx = threadIdx.x, ty = threadIdx.y;  // 32 x 8
    const __hip_bfloat16* src = vb + ((size_t)bk * T_ + t0) * HD_ + h0;
    #pragma unroll
    for (int j = 0; j < 4; j++) tile[ty + j * 8][tx] = src[(size_t)(ty + j * 8) * HD_ + tx];
    __syncthreads();
    __hip_bfloat16* dst = vt + ((size_t)bk * HD_ + h0) * T_ + t0;
    #pragma unroll
    for (int j = 0; j < 4; j++) dst[(size_t)(ty + j * 8) * T_ + tx] = tile[tx][ty + j * 8];
}

// ---------------- causal GQA flash attention ----------------
// Block = 4 waves = 4 GQA q-heads of one (b, kv-head, 32-row q-chunk).
// Depth-2 staging pipeline: 4 LDS buffers, counted s_waitcnt vmcnt(8),
// raw s_barrier (ONE per tile) -- staging issued at iter kt is only waited
// for at iter kt+2, so DMA latency hides under a full tile of compute.
// Complementary chunk pairing: co-resident blocks (bid, bid+256) get chunks
// summing to 65 tiles -> per-CU balance.
__device__ __forceinline__ unsigned pkbf(float a, float b) {
    __hip_bfloat16 x = __float2bfloat16(a), y = __float2bfloat16(b);
    unsigned short xu = *(const unsigned short*)&x, yu = *(const unsigned short*)&y;
    return (unsigned)xu | ((unsigned)yu << 16);
}

union U8u { unsigned u[4]; bf16x8 v; };

__global__ __launch_bounds__(256, 2)
void attn_fwd(const __hip_bfloat16* __restrict__ qb, const __hip_bfloat16* __restrict__ kb,
              const __hip_bfloat16* __restrict__ vt, __hip_bfloat16* __restrict__ yb) {
    __shared__ __attribute__((aligned(16))) __hip_bfloat16 Ks[4][4096];  // 8KB per buf
    __shared__ __attribute__((aligned(16))) __hip_bfloat16 Vs[4][4096];  // 8KB per buf
    const int tid  = threadIdx.x;
    const int w    = tid >> 6, lane = tid & 63;
    const int l31  = lane & 31, hi = lane >> 5;
    const int bid  = blockIdx.x;
    const int strm = bid & 7;              // = b*4 + kvh (XCD-grouped K/V stream)
    const int b    = strm >> 2, kvh = strm & 3;
    const int idx  = bid >> 3;             // 0..63
    const int c    = (idx < 32) ? (63 - idx) : (idx - 32);  // pair (idx, idx+32): 65 tiles/CU
    const int h    = kvh * 4 + w;          // wave = GQA head
    const int qa   = c * 32;

    const __hip_bfloat16* qp = qb + ((size_t)(b * NH_ + h) * T_ + qa) * HD_;
    const __hip_bfloat16* kp = kb + (size_t)(b * NKV_ + kvh) * T_ * HD_;
    const __hip_bfloat16* vp = vt + (size_t)(b * NKV_ + kvh) * HD_ * T_;

    // per-thread staging source coordinates (constant across tiles)
    const int k_hs = tid >> 5, k_kv = tid & 31;       // K chunk u = tid
    const int v_kg = tid >> 7, v_d  = tid & 127;      // V chunk u = tid
    const __hip_bfloat16* ksrc0 = kp + (size_t)k_kv * HD_ + k_hs * 8;
    const __hip_bfloat16* ksrc1 = kp + (size_t)k_kv * HD_ + (8 + k_hs) * 8;
    const __hip_bfloat16* vsrc0 = vp + (size_t)v_d * T_ + v_kg * 8;
    const __hip_bfloat16* vsrc1 = vp + (size_t)v_d * T_ + (2 + v_kg) * 8;

    auto stage = [&](int kt, int bf) {
        const int kvb = kt * 32;
        __hip_bfloat16* kd = &Ks[bf][w * 512];
        __hip_bfloat16* vd = &Vs[bf][w * 512];
        gload_lds16(ksrc0 + (size_t)kvb * HD_, kd);
        gload_lds16(ksrc1 + (size_t)kvb * HD_, kd + 2048);
        gload_lds16(vsrc0 + kvb,               vd);
        gload_lds16(vsrc1 + kvb,               vd + 2048);
    };

    bf16x8 qfr[8];
    #pragma unroll
    for (int hb = 0; hb < 8; ++hb)
        qfr[hb] = *(const bf16x8*)(qp + (size_t)l31 * HD_ + hb * 16 + hi * 8);

    f32x16 o0 = {}, o1 = {}, o2 = {}, o3 = {};
    float m = -1e30f, s = 0.f;

    stage(0, 0);
    stage(c < 1 ? c : 1, 1);

    for (int kt = 0; kt <= c; ++kt) {
        // issue stage kt+2 (always 4 loads -> vmcnt counting stays exact)
        stage(kt + 2 < c ? kt + 2 : c, (kt + 2) & 3);
        // wait until only the newest 8 vmem ops remain -> stage(kt) complete
        asm volatile("s_waitcnt vmcnt(8)" ::: "memory");
        __builtin_amdgcn_s_barrier();
        __builtin_amdgcn_sched_barrier(0);

        const __hip_bfloat16* Kb = &Ks[kt & 3][0];
        const __hip_bfloat16* Vb = &Vs[kt & 3][0];

        // S^T[kv][q] = sum_hd K[kv][hd] * Q[q][hd]  (two independent 4-chains)
        f32x16 sa_a = {}, sa_b = {};
        __builtin_amdgcn_s_setprio(1);
        #pragma unroll
        for (int hb = 0; hb < 4; ++hb) {
            bf16x8 kf = *(const bf16x8*)&Kb[((hb * 2 + hi) * 32 + l31) * 8];
            sa_a = __builtin_amdgcn_mfma_f32_32x32x16_bf16(kf, qfr[hb], sa_a, 0, 0, 0);
        }
        #pragma unroll
        for (int hb = 4; hb < 8; ++hb) {
            bf16x8 kf = *(const bf16x8*)&Kb[((hb * 2 + hi) * 32 + l31) * 8];
            sa_b = __builtin_amdgcn_mfma_f32_32x32x16_bf16(kf, qfr[hb], sa_b, 0, 0, 0);
        }
        __builtin_amdgcn_s_setprio(0);
        f32x16 sa = sa_a + sa_b;

        if (kt == c) {  // diagonal tile: mask kv > q (relative indices)
            #pragma unroll
            for (int r = 0; r < 16; ++r) {
                int kvrel = (r & 3) + 8 * (r >> 2) + 4 * hi;
                if (kvrel > l31) sa[r] = -1e30f;
            }
        }
        float pm = sa[0];
        #pragma unroll
        for (int r = 1; r < 16; ++r) pm = fmaxf(pm, sa[r]);
        pm = fmaxf(pm, __shfl_xor(pm, 32));
        if (!__all(pm <= m + 8.f)) {   // deferred rescale (THR=8, log2 domain)
            float mn = fmaxf(m, pm);
            float corr = exp2f(m - mn);
            s *= corr;
            #pragma unroll
            for (int r = 0; r < 16; ++r) { o0[r] *= corr; o1[r] *= corr; o2[r] *= corr; o3[r] *= corr; }
            m = mn;
        }
        float p[16]; float rs = 0.f;
        #pragma unroll
        for (int r = 0; r < 16; ++r) { p[r] = exp2f(sa[r] - m); rs += p[r]; }
        rs += __shfl_xor(rs, 32);
        s += rs;
        // pack P -> bf16 PV B-fragments (lane pair l <-> l^32 exchange)
        unsigned pk[8];
        #pragma unroll
        for (int jj = 0; jj < 8; ++jj) pk[jj] = pkbf(p[2 * jj], p[2 * jj + 1]);
        unsigned pks[8];
        #pragma unroll
        for (int jj = 0; jj < 8; ++jj) pks[jj] = (unsigned)__shfl_xor((int)pk[jj], 32);
        U8u pa0, pa1;
        pa0.u[0] = hi ? pks[2] : pk[0];
        pa0.u[1] = hi ? pks[3] : pk[1];
        pa0.u[2] = hi ? pk[2]  : pks[0];
        pa0.u[3] = hi ? pk[3]  : pks[1];
        pa1.u[0] = hi ? pks[6] : pk[4];
        pa1.u[1] = hi ? pks[7] : pk[5];
        pa1.u[2] = hi ? pk[6]  : pks[4];
        pa1.u[3] = hi ? pk[7]  : pks[5];
        // O^T[d][q] += V^T[d][kv] * P[kv][q]
        __builtin_amdgcn_s_setprio(1);
        #define PV_BLK(ON, DBLK)                                                              \
            {                                                                                 \
                bf16x8 vf0 = *(const bf16x8*)&Vb[((0 + hi) * 128 + (DBLK) * 32 + l31) * 8];   \
                bf16x8 vf1 = *(const bf16x8*)&Vb[((2 + hi) * 128 + (DBLK) * 32 + l31) * 8];   \
                ON = __builtin_amdgcn_mfma_f32_32x32x16_bf16(vf0, pa0.v, ON, 0, 0, 0);        \
                ON = __builtin_amdgcn_mfma_f32_32x32x16_bf16(vf1, pa1.v, ON, 0, 0, 0);        \
            }
        PV_BLK(o0, 0) PV_BLK(o1, 1) PV_BLK(o2, 2) PV_BLK(o3, 3)
        #undef PV_BLK
        __builtin_amdgcn_s_setprio(0);
    }

    float inv = 1.0f / s;
    __hip_bfloat16* yrow = yb + ((size_t)b * T_ + qa + l31) * D_ + h * HD_;
    #define WRITE_DB(ON, DB)                                                        \
        _Pragma("unroll")                                                           \
        for (int r4 = 0; r4 < 4; ++r4) {                                            \
            ushort4 u;                                                              \
            __hip_bfloat16 e0 = __float2bfloat16(ON[4*r4+0] * inv);                 \
            __hip_bfloat16 e1 = __float2bfloat16(ON[4*r4+1] * inv);                 \
            __hip_bfloat16 e2 = __float2bfloat16(ON[4*r4+2] * inv);                 \
            __hip_bfloat16 e3 = __float2bfloat16(ON[4*r4+3] * inv);                 \
            u.x = *(const unsigned short*)&e0; u.y = *(const unsigned short*)&e1;   \
            u.z = *(const unsigned short*)&e2; u.w = *(const unsigned short*)&e3;   \
            *(ushort4*)(yrow + (DB) * 32 + 8 * r4 + 4 * hi) = u;                    \
        }
    WRITE_DB(o0, 0) WRITE_DB(o1, 1) WRITE_DB(o2, 2) WRITE_DB(o3, 3)
    #undef WRITE_DB
}

extern "C" void kernel_launch(void* const* d_in, const int* in_sizes, int n_in,
                              void* d_out, int out_size, void* d_ws, size_t ws_size,
                              hipStream_t stream) {
    (void)in_sizes; (void)n_in; (void)out_size; (void)ws_size;
    const float* x  = (const float*)d_in[0];
    const float* wq = (const float*)d_in[1];
    const float* wk = (const float*)d_in[2];
    const float* wv = (const float*)d_in[3];
    const float* wp = (const float*)d_in[4];
    const float* qg = (const float*)d_in[5];
    float* out = (float*)d_out;

    char* ws = (char*)d_ws;
    size_t off = 0;
    auto alloc = [&](size_t bytes) { char* p = ws + off; off += (bytes + 255) & ~(size_t)255; return p; };

    __hip_bfloat16* xb  = (__hip_bfloat16*)alloc((size_t)BT_ * D_ * 2);
    __hip_bfloat16* wqb = (__hip_bfloat16*)alloc((size_t)D_ * D_ * 2);
    __hip_bfloat16* wkb = (__hip_bfloat16*)alloc((size_t)KD_ * D_ * 2);
    __hip_bfloat16* wvb = (__hip_bfloat16*)alloc((size_t)KD_ * D_ * 2);
    __hip_bfloat16* wpb = (__hip_bfloat16*)alloc((size_t)D_ * D_ * 2);
    float* qf = (float*)alloc((size_t)BT_ * D_ * 4);
    float* kf = (float*)alloc((size_t)BT_ * KD_ * 4);
    float* vf = (float*)alloc((size_t)BT_ * KD_ * 4);
    __hip_bfloat16* qbb = (__hip_bfloat16*)alloc((size_t)BT_ * D_ * 2);
    __hip_bfloat16* kbb = (__hip_bfloat16*)alloc((size_t)BT_ * KD_ * 2);
    // aliases (lifetimes disjoint on the sequential stream):
    __hip_bfloat16* ybb = xb;                   // yb written after xb's last read
    __hip_bfloat16* vbb = wqb;                  // wqb dead after q-projection
    __hip_bfloat16* vtb = wqb + (size_t)B_ * NKV_ * T_ * HD_;

    f2b_kernel<<<2048, 256, 0, stream>>>((const float4*)x,  (ushort4*)xb,  BT_ * D_ / 4);
    f2b_kernel<<<2048, 256, 0, stream>>>((const float4*)wq, (ushort4*)wqb, D_ * D_ / 4);
    f2b_kernel<<<2048, 256, 0, stream>>>((const float4*)wk, (ushort4*)wkb, KD_ * D_ / 4);
    f2b_kernel<<<2048, 256, 0, stream>>>((const float4*)wv, (ushort4*)wvb, KD_ * D_ / 4);
    f2b_kernel<<<2048, 256, 0, stream>>>((const float4*)wp, (ushort4*)wpb, D_ * D_ / 4);

    dim3 gq(BT_ / 128, D_ / 128);
    gemm_bt<<<gq, 256, 0, stream>>>(xb, wqb, qf, BT_, D_, D_);
    dim3 gkv(BT_ / 128, KD_ / 128);
    gemm_bt<<<gkv, 256, 0, stream>>>(xb, wkb, kf, BT_, KD_, D_);
    gemm_bt<<<gkv, 256, 0, stream>>>(xb, wvb, vf, BT_, KD_, D_);

    norm_rope<<<(BT_ * 24) / 4, 256, 0, stream>>>(qf, kf, vf, qg, qbb, kbb, vbb);

    dim3 gt(T_ / 32, HD_ / 32, B_ * NKV_);
    vtrans<<<gt, dim3(32, 8), 0, stream>>>(vbb, vtb);

    attn_fwd<<<512, 256, 0, stream>>>(qbb, kbb, vtb, ybb);

    gemm_bt<<<gq, 256, 0, stream>>>(ybb, wpb, out, BT_, D_, D_);
}

// Round 7
// 317.274 us; speedup vs baseline: 1.4034x; 1.0509x over previous
//
#include <hip/hip_runtime.h>
#include <hip/hip_bf16.h>

#define B_   2
#define T_   2048
#define D_   2048
#define NH_  16
#define NKV_ 4
#define HD_  128
#define KD_  512   // NKV*HD
#define BT_  4096  // B_*T_

typedef __bf16 bf16x8 __attribute__((ext_vector_type(8)));
typedef float  f32x4  __attribute__((ext_vector_type(4)));
typedef float  f32x16 __attribute__((ext_vector_type(16)));

__device__ __forceinline__ void gload_lds16(const __hip_bfloat16* g, __hip_bfloat16* l) {
    __builtin_amdgcn_global_load_lds(
        (__attribute__((address_space(1))) void*)(g),
        (__attribute__((address_space(3))) void*)(l),
        16, 0, 0);
}

// ---------------- fp32 -> bf16 convert (all 5 tensors, one launch) ----------------
__global__ void f2b_all(const float4* __restrict__ x,  const float4* __restrict__ wq,
                        const float4* __restrict__ wk, const float4* __restrict__ wv,
                        const float4* __restrict__ wp,
                        ushort4* __restrict__ xb,  ushort4* __restrict__ wqb,
                        ushort4* __restrict__ wkb, ushort4* __restrict__ wvb,
                        ushort4* __restrict__ wpb) {
    const int e0 = BT_ * D_ / 4;              // 2097152
    const int e1 = e0 + D_ * D_ / 4;          // 3145728
    const int e2 = e1 + KD_ * D_ / 4;         // 3407872
    const int e3 = e2 + KD_ * D_ / 4;         // 3670016
    const int e4 = e3 + D_ * D_ / 4;          // 4718592
    int idx = blockIdx.x * blockDim.x + threadIdx.x;
    int stride = gridDim.x * blockDim.x;
    for (int j = idx; j < e4; j += stride) {
        const float4* src; ushort4* dst; int off;
        if      (j < e0) { src = x;  dst = xb;  off = j; }
        else if (j < e1) { src = wq; dst = wqb; off = j - e0; }
        else if (j < e2) { src = wk; dst = wkb; off = j - e1; }
        else if (j < e3) { src = wv; dst = wvb; off = j - e2; }
        else             { src = wp; dst = wpb; off = j - e3; }
        float4 v = src[off];
        __hip_bfloat16 a = __float2bfloat16(v.x), b = __float2bfloat16(v.y),
                       c = __float2bfloat16(v.z), d = __float2bfloat16(v.w);
        ushort4 o;
        o.x = *(const unsigned short*)&a; o.y = *(const unsigned short*)&b;
        o.z = *(const unsigned short*)&c; o.w = *(const unsigned short*)&d;
        dst[off] = o;
    }
}

// ---------------- GEMM: C(MxN) = A(MxK) * B(NxK)^T, bf16 in, f32 out ----------------
__global__ __launch_bounds__(256)
void gemm_bt(const __hip_bfloat16* __restrict__ A, const __hip_bfloat16* __restrict__ B,
             float* __restrict__ C, int M, int N, int K) {
    __shared__ __attribute__((aligned(16))) __hip_bfloat16 As[128 * 32];
    __shared__ __attribute__((aligned(16))) __hip_bfloat16 Bs[128 * 32];
    const int tid  = threadIdx.x;
    const int w    = tid >> 6;
    const int lane = tid & 63;
    const int lr   = lane & 15;
    const int lk   = lane >> 4;
    const int wr   = w >> 1, wc = w & 1;
    const size_t row0 = (size_t)blockIdx.x * 128;
    const size_t col0 = (size_t)blockIdx.y * 128;

    const __hip_bfloat16* ga = A + (row0 + tid / 4) * K + (tid % 4) * 8;
    const __hip_bfloat16* gb = B + (col0 + tid / 4) * K + (tid % 4) * 8;
    __hip_bfloat16* lA0 = &As[w * 512];
    __hip_bfloat16* lA1 = &As[2048 + w * 512];
    __hip_bfloat16* lB0 = &Bs[w * 512];
    __hip_bfloat16* lB1 = &Bs[2048 + w * 512];

    f32x4 acc[4][4] = {};
    for (int k0 = 0; k0 < K; k0 += 32) {
        gload_lds16(ga + k0,                 lA0);
        gload_lds16(ga + k0 + (size_t)64*K,  lA1);
        gload_lds16(gb + k0,                 lB0);
        gload_lds16(gb + k0 + (size_t)64*K,  lB1);
        __syncthreads();
        bf16x8 af[4], bfr[4];
        #pragma unroll
        for (int m = 0; m < 4; m++)
            af[m] = *(const bf16x8*)&As[(wr * 64 + m * 16 + lr) * 32 + lk * 8];
        #pragma unroll
        for (int n = 0; n < 4; n++)
            bfr[n] = *(const bf16x8*)&Bs[(wc * 64 + n * 16 + lr) * 32 + lk * 8];
        #pragma unroll
        for (int m = 0; m < 4; m++)
            #pragma unroll
            for (int n = 0; n < 4; n++)
                acc[m][n] = __builtin_amdgcn_mfma_f32_16x16x32_bf16(af[m], bfr[n], acc[m][n], 0, 0, 0);
        __syncthreads();
    }
    #pragma unroll
    for (int m = 0; m < 4; m++)
        #pragma unroll
        for (int n = 0; n < 4; n++)
            #pragma unroll
            for (int r = 0; r < 4; r++)
                C[(row0 + wr * 64 + m * 16 + lk * 4 + r) * N + col0 + wc * 64 + n * 16 + lr] = acc[m][n][r];
}

// ---------------- RMSNorm + partial RoPE + gain; v passthrough to bf16 ----------------
__global__ __launch_bounds__(256)
void norm_rope(const float* __restrict__ qf, const float* __restrict__ kf, const float* __restrict__ vf,
               const float* __restrict__ qg,
               __hip_bfloat16* __restrict__ qb, __hip_bfloat16* __restrict__ kb, __hip_bfloat16* __restrict__ vb) {
    int wid  = (blockIdx.x * 256 + threadIdx.x) >> 6;
    int lane = threadIdx.x & 63;
    int bt = wid / 24, hh = wid % 24;
    int b = bt >> 11, t = bt & (T_ - 1);

    const float* row;
    if (hh < NH_)            row = qf + (size_t)bt * D_  + hh * HD_;
    else if (hh < NH_+NKV_)  row = kf + (size_t)bt * KD_ + (hh - NH_) * HD_;
    else                     row = vf + (size_t)bt * KD_ + (hh - NH_ - NKV_) * HD_;

    float2 xv = *(const float2*)(row + lane * 2);

    if (hh >= NH_ + NKV_) {  // v: just convert
        int kv = hh - NH_ - NKV_;
        __hip_bfloat16* o = vb + ((size_t)(b * NKV_ + kv) * T_ + t) * HD_ + lane * 2;
        o[0] = __float2bfloat16(xv.x); o[1] = __float2bfloat16(xv.y);
        return;
    }

    float ss = xv.x * xv.x + xv.y * xv.y;
    #pragma unroll
    for (int off = 32; off; off >>= 1) ss += __shfl_xor(ss, off);
    float rn = rsqrtf(ss * (1.0f / HD_) + 1.1920929e-7f);
    float y0 = xv.x * rn, y1 = xv.y * rn;

    float py0 = __shfl_xor(y0, 4), py1 = __shfl_xor(y1, 4);
    float o0 = y0, o1 = y1;
    if (lane < 8) {
        int i0 = (2 * lane) & 7;
        float f0 = (float)t * exp2f(-(float)i0       * 1.66096404744368f);
        float f1 = (float)t * exp2f(-(float)(i0 + 1) * 1.66096404744368f);
        float s0, c0, s1, c1;
        sincosf(f0, &s0, &c0);
        sincosf(f1, &s1, &c1);
        if (lane < 4) { o0 =  y0 * c0 + py0 * s0; o1 =  y1 * c1 + py1 * s1; }
        else          { o0 = -y0 * c0 + py0 * s0; o1 = -y1 * c1 + py1 * s1; }
    }

    if (hh < NH_) {
        // fold gain * 1/sqrt(HD) * log2(e) into q
        float g = qg[hh] * 0.1275174305f;
        o0 *= g; o1 *= g;
        __hip_bfloat16* o = qb + ((size_t)(b * NH_ + hh) * T_ + t) * HD_ + lane * 2;
        o[0] = __float2bfloat16(o0); o[1] = __float2bfloat16(o1);
    } else {
        int kv = hh - NH_;
        __hip_bfloat16* o = kb + ((size_t)(b * NKV_ + kv) * T_ + t) * HD_ + lane * 2;
        o[0] = __float2bfloat16(o0); o[1] = __float2bfloat16(o1);
    }
}

// ---------------- V transpose: [bk][T][HD] -> [bk][HD][T] ----------------
__global__ void vtrans(const __hip_bfloat16* __restrict__ vb, __hip_bfloat16* __restrict__ vt) {
    __shared__ __hip_bfloat16 tile[32][33];
    int bk = blockIdx.z;
    int t0 = blockIdx.x * 32, h0 = blockIdx.y * 32;
    int tx = threadIdx.x, ty = threadIdx.y;  // 32 x 8
    const __hip_bfloat16* src = vb + ((size_t)bk * T_ + t0) * HD_ + h0;
    #pragma unroll
    for (int j = 0; j < 4; j++) tile[ty + j * 8][tx] = src[(size_t)(ty + j * 8) * HD_ + tx];
    __syncthreads();
    __hip_bfloat16* dst = vt + ((size_t)bk * HD_ + h0) * T_ + t0;
    #pragma unroll
    for (int j = 0; j < 4; j++) dst[(size_t)(ty + j * 8) * T_ + tx] = tile[tx][ty + j * 8];
}

// ---------------- causal GQA flash attention ----------------
// Block = 8 waves = 4 GQA heads x 2 KV-SEGMENTS of one (b, kv-head, 32-row chunk c).
// seg0: tiles [0, ns), seg1: tiles [ns, c], ns = ceil((c+1)/2) -- equal length
// (seg1 padded with fully-masked iters). All 8 waves run uniform lockstep;
// both segments' tiles staged per iter (512 thr x 4 loads), depth-2 pipeline
// (4 slots, counted vmcnt(8), raw s_barrier). End: seg1 partials (m,s,O)
// merged into seg0 via LDS (staging space reused after vmcnt(0)+barrier).
// Grid: c = 63-2*idx (idx<32) else 126-2*idx -> greedy dispatch pairs every
// CU's 2 blocks to ns1+ns2 = 33 iters.
__device__ __forceinline__ unsigned pkbf(float a, float b) {
    __hip_bfloat16 x = __float2bfloat16(a), y = __float2bfloat16(b);
    unsigned short xu = *(const unsigned short*)&x, yu = *(const unsigned short*)&y;
    return (unsigned)xu | ((unsigned)yu << 16);
}

union U8u { unsigned u[4]; bf16x8 v; };

__global__ __launch_bounds__(512, 2)
void attn_fwd(const __hip_bfloat16* __restrict__ qb, const __hip_bfloat16* __restrict__ kb,
              const __hip_bfloat16* __restrict__ vt, __hip_bfloat16* __restrict__ yb) {
    __shared__ __attribute__((aligned(16))) __hip_bfloat16 Ks[2][4][4096];  // 64KB
    __shared__ __attribute__((aligned(16))) __hip_bfloat16 Vs[2][4][4096];  // 64KB
    const int tid  = threadIdx.x;
    const int w    = tid >> 6, lane = tid & 63;
    const int l31  = lane & 31, hi = lane >> 5;
    const int hd4  = w & 3;                // head within kv group
    const int seg  = w >> 2;               // KV segment 0/1
    const int bid  = blockIdx.x;
    const int strm = bid & 7;              // = b*4 + kvh (XCD-grouped K/V stream)
    const int b    = strm >> 2, kvh = strm & 3;
    const int idx  = bid >> 3;             // 0..63
    const int c    = (idx < 32) ? (63 - 2 * idx) : (126 - 2 * idx);
    const int ns   = (c >> 1) + 1;         // iters per segment
    const int h    = kvh * 4 + hd4;
    const int qa   = c * 32;

    const __hip_bfloat16* qp = qb + ((size_t)(b * NH_ + h) * T_ + qa) * HD_;
    const __hip_bfloat16* kp = kb + (size_t)(b * NKV_ + kvh) * T_ * HD_;
    const __hip_bfloat16* vp = vt + (size_t)(b * NKV_ + kvh) * HD_ * T_;

    // staging: thread tt of segment sg covers 4x16B of that seg's (K,V) tile
    const int tt = tid & 255, sg = tid >> 8;
    const int k_hs = tt >> 5, k_kv = tt & 31;
    const int v_kg = tt >> 7, v_d  = tt & 127;
    const __hip_bfloat16* ksrc0 = kp + (size_t)k_kv * HD_ + k_hs * 8;
    const __hip_bfloat16* ksrc1 = kp + (size_t)k_kv * HD_ + (8 + k_hs) * 8;
    const __hip_bfloat16* vsrc0 = vp + (size_t)v_d * T_ + v_kg * 8;
    const __hip_bfloat16* vsrc1 = vp + (size_t)v_d * T_ + (2 + v_kg) * 8;

    auto stage = [&](int u) {
        int kt0 = u < ns - 1 ? u : ns - 1;
        int kt1 = ns + u; if (kt1 > c) kt1 = c;
        const int kvb = (sg ? kt1 : kt0) * 32;
        const int slot = u & 3;
        __hip_bfloat16* kd = &Ks[sg][slot][(tt >> 6) * 512];
        __hip_bfloat16* vd = &Vs[sg][slot][(tt >> 6) * 512];
        gload_lds16(ksrc0 + (size_t)kvb * HD_, kd);
        gload_lds16(ksrc1 + (size_t)kvb * HD_, kd + 2048);
        gload_lds16(vsrc0 + kvb,               vd);
        gload_lds16(vsrc1 + kvb,               vd + 2048);
    };

    bf16x8 qfr[8];
    #pragma unroll
    for (int hb = 0; hb < 8; ++hb)
        qfr[hb] = *(const bf16x8*)(qp + (size_t)l31 * HD_ + hb * 16 + hi * 8);

    f32x16 o0 = {}, o1 = {}, o2 = {}, o3 = {};
    float m = -1e30f, s = 0.f;

    stage(0);
    stage(1);

    for (int t = 0; t < ns; ++t) {
        stage(t + 2);
        asm volatile("s_waitcnt vmcnt(8)" ::: "memory");
        __builtin_amdgcn_s_barrier();
        __builtin_amdgcn_sched_barrier(0);

        const int kt_raw = seg ? ns + t : t;
        const bool dead  = kt_raw > c;
        const int kt     = dead ? c : kt_raw;

        const __hip_bfloat16* Kb = &Ks[seg][t & 3][0];
        const __hip_bfloat16* Vb = &Vs[seg][t & 3][0];

        // S^T[kv][q] = sum_hd K[kv][hd] * Q[q][hd]  (two independent 4-chains)
        f32x16 sa_a = {}, sa_b = {};
        __builtin_amdgcn_s_setprio(1);
        #pragma unroll
        for (int hb = 0; hb < 4; ++hb) {
            bf16x8 kf = *(const bf16x8*)&Kb[((hb * 2 + hi) * 32 + l31) * 8];
            sa_a = __builtin_amdgcn_mfma_f32_32x32x16_bf16(kf, qfr[hb], sa_a, 0, 0, 0);
        }
        #pragma unroll
        for (int hb = 4; hb < 8; ++hb) {
            bf16x8 kf = *(const bf16x8*)&Kb[((hb * 2 + hi) * 32 + l31) * 8];
            sa_b = __builtin_amdgcn_mfma_f32_32x32x16_bf16(kf, qfr[hb], sa_b, 0, 0, 0);
        }
        __builtin_amdgcn_s_setprio(0);
        f32x16 sa = sa_a + sa_b;

        if (dead) {
            #pragma unroll
            for (int r = 0; r < 16; ++r) sa[r] = -1e30f;
        } else if (kt == c) {  // diagonal tile: mask kv > q (relative indices)
            #pragma unroll
            for (int r = 0; r < 16; ++r) {
                int kvrel = (r & 3) + 8 * (r >> 2) + 4 * hi;
                if (kvrel > l31) sa[r] = -1e30f;
            }
        }
        float pm = sa[0];
        #pragma unroll
        for (int r = 1; r < 16; ++r) pm = fmaxf(pm, sa[r]);
        pm = fmaxf(pm, __shfl_xor(pm, 32));
        if (!__all(pm <= m + 8.f)) {   // deferred rescale (THR=8, log2 domain)
            float mn = fmaxf(m, pm);
            float corr = exp2f(m - mn);
            s *= corr;
            #pragma unroll
            for (int r = 0; r < 16; ++r) { o0[r] *= corr; o1[r] *= corr; o2[r] *= corr; o3[r] *= corr; }
            m = mn;
        }
        float p[16]; float rs = 0.f;
        #pragma unroll
        for (int r = 0; r < 16; ++r) { p[r] = exp2f(sa[r] - m); rs += p[r]; }
        rs += __shfl_xor(rs, 32);
        s += rs;
        // pack P -> bf16 PV B-fragments (lane pair l <-> l^32 exchange)
        unsigned pk[8];
        #pragma unroll
        for (int jj = 0; jj < 8; ++jj) pk[jj] = pkbf(p[2 * jj], p[2 * jj + 1]);
        unsigned pks[8];
        #pragma unroll
        for (int jj = 0; jj < 8; ++jj) pks[jj] = (unsigned)__shfl_xor((int)pk[jj], 32);
        U8u pa0, pa1;
        pa0.u[0] = hi ? pks[2] : pk[0];
        pa0.u[1] = hi ? pks[3] : pk[1];
        pa0.u[2] = hi ? pk[2]  : pks[0];
        pa0.u[3] = hi ? pk[3]  : pks[1];
        pa1.u[0] = hi ? pks[6] : pk[4];
        pa1.u[1] = hi ? pks[7] : pk[5];
        pa1.u[2] = hi ? pk[6]  : pks[4];
        pa1.u[3] = hi ? pk[7]  : pks[5];
        // O^T[d][q] += V^T[d][kv] * P[kv][q]
        __builtin_amdgcn_s_setprio(1);
        #define PV_BLK(ON, DBLK)                                                              \
            {                                                                                 \
                bf16x8 vf0 = *(const bf16x8*)&Vb[((0 + hi) * 128 + (DBLK) * 32 + l31) * 8];   \
                bf16x8 vf1 = *(const bf16x8*)&Vb[((2 + hi) * 128 + (DBLK) * 32 + l31) * 8];   \
                ON = __builtin_amdgcn_mfma_f32_32x32x16_bf16(vf0, pa0.v, ON, 0, 0, 0);        \
                ON = __builtin_amdgcn_mfma_f32_32x32x16_bf16(vf1, pa1.v, ON, 0, 0, 0);        \
            }
        PV_BLK(o0, 0) PV_BLK(o1, 1) PV_BLK(o2, 2) PV_BLK(o3, 3)
        #undef PV_BLK
        __builtin_amdgcn_s_setprio(0);
    }

    // ---- merge seg1 -> seg0 through LDS (reuse staging space) ----
    asm volatile("s_waitcnt vmcnt(0)" ::: "memory");  // all staging DMAs landed
    __syncthreads();
    // head 0,1 partials in Ks; head 2,3 in Vs. Region: 4096 O + 64 m + 64 s floats.
    float* Mh = (hd4 < 2) ? ((float*)&Ks[0][0][0] + hd4 * 4352)
                          : ((float*)&Vs[0][0][0] + (hd4 - 2) * 4352);
    if (seg == 1) {
        #pragma unroll
        for (int r = 0; r < 16; ++r) {
            Mh[(0 * 16 + r) * 64 + lane] = o0[r];
            Mh[(1 * 16 + r) * 64 + lane] = o1[r];
            Mh[(2 * 16 + r) * 64 + lane] = o2[r];
            Mh[(3 * 16 + r) * 64 + lane] = o3[r];
        }
        Mh[4096 + lane] = m;
        Mh[4160 + lane] = s;
    }
    __syncthreads();
    if (seg == 0) {
        float m1 = Mh[4096 + lane], s1 = Mh[4160 + lane];
        float mn = fmaxf(m, m1);
        float ca = exp2f(m - mn), cb = exp2f(m1 - mn);
        s = s * ca + s1 * cb;
        #pragma unroll
        for (int r = 0; r < 16; ++r) {
            o0[r] = o0[r] * ca + Mh[(0 * 16 + r) * 64 + lane] * cb;
            o1[r] = o1[r] * ca + Mh[(1 * 16 + r) * 64 + lane] * cb;
            o2[r] = o2[r] * ca + Mh[(2 * 16 + r) * 64 + lane] * cb;
            o3[r] = o3[r] * ca + Mh[(3 * 16 + r) * 64 + lane] * cb;
        }
        float inv = 1.0f / s;
        __hip_bfloat16* yrow = yb + ((size_t)b * T_ + qa + l31) * D_ + h * HD_;
        #define WRITE_DB(ON, DB)                                                        \
            _Pragma("unroll")                                                           \
            for (int r4 = 0; r4 < 4; ++r4) {                                            \
                ushort4 u;                                                              \
                __hip_bfloat16 e0 = __float2bfloat16(ON[4*r4+0] * inv);                 \
                __hip_bfloat16 e1 = __float2bfloat16(ON[4*r4+1] * inv);                 \
                __hip_bfloat16 e2 = __float2bfloat16(ON[4*r4+2] * inv);                 \
                __hip_bfloat16 e3 = __float2bfloat16(ON[4*r4+3] * inv);                 \
                u.x = *(const unsigned short*)&e0; u.y = *(const unsigned short*)&e1;   \
                u.z = *(const unsigned short*)&e2; u.w = *(const unsigned short*)&e3;   \
                *(ushort4*)(yrow + (DB) * 32 + 8 * r4 + 4 * hi) = u;                    \
            }
        WRITE_DB(o0, 0) WRITE_DB(o1, 1) WRITE_DB(o2, 2) WRITE_DB(o3, 3)
        #undef WRITE_DB
    }
}

extern "C" void kernel_launch(void* const* d_in, const int* in_sizes, int n_in,
                              void* d_out, int out_size, void* d_ws, size_t ws_size,
                              hipStream_t stream) {
    (void)in_sizes; (void)n_in; (void)out_size; (void)ws_size;
    const float* x  = (const float*)d_in[0];
    const float* wq = (const float*)d_in[1];
    const float* wk = (const float*)d_in[2];
    const float* wv = (const float*)d_in[3];
    const float* wp = (const float*)d_in[4];
    const float* qg = (const float*)d_in[5];
    float* out = (float*)d_out;

    char* ws = (char*)d_ws;
    size_t off = 0;
    auto alloc = [&](size_t bytes) { char* p = ws + off; off += (bytes + 255) & ~(size_t)255; return p; };

    __hip_bfloat16* xb  = (__hip_bfloat16*)alloc((size_t)BT_ * D_ * 2);
    __hip_bfloat16* wqb = (__hip_bfloat16*)alloc((size_t)D_ * D_ * 2);
    __hip_bfloat16* wkb = (__hip_bfloat16*)alloc((size_t)KD_ * D_ * 2);
    __hip_bfloat16* wvb = (__hip_bfloat16*)alloc((size_t)KD_ * D_ * 2);
    __hip_bfloat16* wpb = (__hip_bfloat16*)alloc((size_t)D_ * D_ * 2);
    float* qf = (float*)alloc((size_t)BT_ * D_ * 4);
    float* kf = (float*)alloc((size_t)BT_ * KD_ * 4);
    float* vf = (float*)alloc((size_t)BT_ * KD_ * 4);
    __hip_bfloat16* qbb = (__hip_bfloat16*)alloc((size_t)BT_ * D_ * 2);
    __hip_bfloat16* kbb = (__hip_bfloat16*)alloc((size_t)BT_ * KD_ * 2);
    // aliases (lifetimes disjoint on the sequential stream):
    __hip_bfloat16* ybb = xb;                   // yb written after xb's last read
    __hip_bfloat16* vbb = wqb;                  // wqb dead after q-projection
    __hip_bfloat16* vtb = wqb + (size_t)B_ * NKV_ * T_ * HD_;

    f2b_all<<<2048, 256, 0, stream>>>((const float4*)x, (const float4*)wq, (const float4*)wk,
                                      (const float4*)wv, (const float4*)wp,
                                      (ushort4*)xb, (ushort4*)wqb, (ushort4*)wkb,
                                      (ushort4*)wvb, (ushort4*)wpb);

    dim3 gq(BT_ / 128, D_ / 128);
    gemm_bt<<<gq, 256, 0, stream>>>(xb, wqb, qf, BT_, D_, D_);
    dim3 gkv(BT_ / 128, KD_ / 128);
    gemm_bt<<<gkv, 256, 0, stream>>>(xb, wkb, kf, BT_, KD_, D_);
    gemm_bt<<<gkv, 256, 0, stream>>>(xb, wvb, vf, BT_, KD_, D_);

    norm_rope<<<(BT_ * 24) / 4, 256, 0, stream>>>(qf, kf, vf, qg, qbb, kbb, vbb);

    dim3 gt(T_ / 32, HD_ / 32, B_ * NKV_);
    vtrans<<<gt, dim3(32, 8), 0, stream>>>(vbb, vtb);

    attn_fwd<<<512, 512, 0, stream>>>(qbb, kbb, vtb, ybb);

    gemm_bt<<<gq, 256, 0, stream>>>(ybb, wpb, out, BT_, D_, D_);
}

// Round 8
// 235.413 us; speedup vs baseline: 1.8914x; 1.3477x over previous
//
#include <hip/hip_runtime.h>
#include <hip/hip_bf16.h>

#define B_   2
#define T_   2048
#define D_   2048
#define NH_  16
#define NKV_ 4
#define HD_  128
#define KD_  512   // NKV*HD
#define BT_  4096  // B_*T_

typedef __bf16 bf16x8 __attribute__((ext_vector_type(8)));
typedef float  f32x4  __attribute__((ext_vector_type(4)));
typedef float  f32x16 __attribute__((ext_vector_type(16)));

__device__ __forceinline__ void gload_lds16(const __hip_bfloat16* g, __hip_bfloat16* l) {
    __builtin_amdgcn_global_load_lds(
        (__attribute__((address_space(1))) void*)(g),
        (__attribute__((address_space(3))) void*)(l),
        16, 0, 0);
}

// ---------------- fp32 -> bf16 convert (all 5 tensors, one launch) ----------------
__global__ void f2b_all(const float4* __restrict__ x,  const float4* __restrict__ wq,
                        const float4* __restrict__ wk, const float4* __restrict__ wv,
                        const float4* __restrict__ wp,
                        ushort4* __restrict__ xb,  ushort4* __restrict__ wqb,
                        ushort4* __restrict__ wkb, ushort4* __restrict__ wvb,
                        ushort4* __restrict__ wpb) {
    const int e0 = BT_ * D_ / 4;
    const int e1 = e0 + D_ * D_ / 4;
    const int e2 = e1 + KD_ * D_ / 4;
    const int e3 = e2 + KD_ * D_ / 4;
    const int e4 = e3 + D_ * D_ / 4;
    int idx = blockIdx.x * blockDim.x + threadIdx.x;
    int stride = gridDim.x * blockDim.x;
    for (int j = idx; j < e4; j += stride) {
        const float4* src; ushort4* dst; int off;
        if      (j < e0) { src = x;  dst = xb;  off = j; }
        else if (j < e1) { src = wq; dst = wqb; off = j - e0; }
        else if (j < e2) { src = wk; dst = wkb; off = j - e1; }
        else if (j < e3) { src = wv; dst = wvb; off = j - e2; }
        else             { src = wp; dst = wpb; off = j - e3; }
        float4 v = src[off];
        __hip_bfloat16 a = __float2bfloat16(v.x), b = __float2bfloat16(v.y),
                       c = __float2bfloat16(v.z), d = __float2bfloat16(v.w);
        ushort4 o;
        o.x = *(const unsigned short*)&a; o.y = *(const unsigned short*)&b;
        o.z = *(const unsigned short*)&c; o.w = *(const unsigned short*)&d;
        dst[off] = o;
    }
}

// ================= pipelined 128x128 GEMM tile (depth-2, counted vmcnt) =================
// C(MxN) = A(MxK) * B(NxK)^T, bf16 in, f32 out. 4 LDS slot-pairs; per iter:
// stage(kt+2) -> s_waitcnt vmcnt(8) -> raw s_barrier -> MFMA on slot kt&3.
// (Same pipeline proven in attn_fwd R6: stage kt waited 2 iters after issue.)
#define GEMM_TILE_BODY(Aptr, Bptr, Cptr, colL, Nc, K)                                         \
    const int tid = threadIdx.x, w = tid >> 6, lane = tid & 63;                               \
    const int lr = lane & 15, lk = lane >> 4;                                                 \
    const int wr = w >> 1, wc = w & 1;                                                        \
    const size_t row0 = (size_t)blockIdx.x * 128;                                             \
    const __hip_bfloat16* ga = (Aptr) + (row0 + tid / 4) * (K) + (tid % 4) * 8;               \
    const __hip_bfloat16* gb = (Bptr) + ((size_t)(colL) + tid / 4) * (K) + (tid % 4) * 8;     \
    const int KI = (K) >> 5;                                                                  \
    auto stage = [&](int u) {                                                                 \
        int uu = u < KI ? u : KI - 1;                                                         \
        const int kk = uu * 32;                                                               \
        const int slot = u & 3;                                                               \
        gload_lds16(ga + kk,                  &As[slot][w * 512]);                            \
        gload_lds16(ga + kk + (size_t)64*(K), &As[slot][2048 + w * 512]);                     \
        gload_lds16(gb + kk,                  &Bs[slot][w * 512]);                            \
        gload_lds16(gb + kk + (size_t)64*(K), &Bs[slot][2048 + w * 512]);                     \
    };                                                                                        \
    f32x4 acc[4][4] = {};                                                                     \
    stage(0); stage(1);                                                                       \
    for (int kt = 0; kt < KI; ++kt) {                                                         \
        stage(kt + 2);                                                                        \
        asm volatile("s_waitcnt vmcnt(8)" ::: "memory");                                      \
        __builtin_amdgcn_s_barrier();                                                         \
        __builtin_amdgcn_sched_barrier(0);                                                    \
        const int slot = kt & 3;                                                              \
        bf16x8 af[4], bfr[4];                                                                 \
        _Pragma("unroll")                                                                     \
        for (int m = 0; m < 4; m++)                                                           \
            af[m] = *(const bf16x8*)&As[slot][(wr * 64 + m * 16 + lr) * 32 + lk * 8];         \
        _Pragma("unroll")                                                                     \
        for (int n = 0; n < 4; n++)                                                           \
            bfr[n] = *(const bf16x8*)&Bs[slot][(wc * 64 + n * 16 + lr) * 32 + lk * 8];        \
        _Pragma("unroll")                                                                     \
        for (int m = 0; m < 4; m++)                                                           \
            _Pragma("unroll")                                                                 \
            for (int n = 0; n < 4; n++)                                                       \
                acc[m][n] = __builtin_amdgcn_mfma_f32_16x16x32_bf16(af[m], bfr[n],            \
                                                                    acc[m][n], 0, 0, 0);      \
    }                                                                                         \
    _Pragma("unroll")                                                                         \
    for (int m = 0; m < 4; m++)                                                               \
        _Pragma("unroll")                                                                     \
        for (int n = 0; n < 4; n++)                                                           \
            _Pragma("unroll")                                                                 \
            for (int r = 0; r < 4; r++)                                                       \
                (Cptr)[(row0 + wr * 64 + m * 16 + lk * 4 + r) * (Nc)                          \
                       + (colL) + wc * 64 + n * 16 + lr] = acc[m][n][r];

// Fused q/k/v projection: virtual N = 3072 (16 q-col-blocks, 4 k, 4 v)
__global__ __launch_bounds__(256, 2)
void gemm_qkv(const __hip_bfloat16* __restrict__ A,
              const __hip_bfloat16* __restrict__ Wq, const __hip_bfloat16* __restrict__ Wk,
              const __hip_bfloat16* __restrict__ Wv,
              float* __restrict__ Cq, float* __restrict__ Ck, float* __restrict__ Cv) {
    __shared__ __attribute__((aligned(16))) __hip_bfloat16 As[4][4096];
    __shared__ __attribute__((aligned(16))) __hip_bfloat16 Bs[4][4096];
    const int cb = blockIdx.y;
    const __hip_bfloat16* Bw; float* Cm; int Nc, colL;
    if (cb < 16)      { Bw = Wq; Cm = Cq; Nc = D_;  colL = cb * 128; }
    else if (cb < 20) { Bw = Wk; Cm = Ck; Nc = KD_; colL = (cb - 16) * 128; }
    else              { Bw = Wv; Cm = Cv; Nc = KD_; colL = (cb - 20) * 128; }
    GEMM_TILE_BODY(A, Bw, Cm, colL, Nc, D_)
}

// Plain pipelined GEMM (output projection)
__global__ __launch_bounds__(256, 2)
void gemm_p(const __hip_bfloat16* __restrict__ A, const __hip_bfloat16* __restrict__ B,
            float* __restrict__ C, int N, int K) {
    __shared__ __attribute__((aligned(16))) __hip_bfloat16 As[4][4096];
    __shared__ __attribute__((aligned(16))) __hip_bfloat16 Bs[4][4096];
    const int colL = blockIdx.y * 128;
    GEMM_TILE_BODY(A, B, C, colL, N, K)
}

// ---------------- RMSNorm + partial RoPE + gain; v passthrough to bf16 ----------------
__global__ __launch_bounds__(256)
void norm_rope(const float* __restrict__ qf, const float* __restrict__ kf, const float* __restrict__ vf,
               const float* __restrict__ qg,
               __hip_bfloat16* __restrict__ qb, __hip_bfloat16* __restrict__ kb, __hip_bfloat16* __restrict__ vb) {
    int wid  = (blockIdx.x * 256 + threadIdx.x) >> 6;
    int lane = threadIdx.x & 63;
    int bt = wid / 24, hh = wid % 24;
    int b = bt >> 11, t = bt & (T_ - 1);

    const float* row;
    if (hh < NH_)            row = qf + (size_t)bt * D_  + hh * HD_;
    else if (hh < NH_+NKV_)  row = kf + (size_t)bt * KD_ + (hh - NH_) * HD_;
    else                     row = vf + (size_t)bt * KD_ + (hh - NH_ - NKV_) * HD_;

    float2 xv = *(const float2*)(row + lane * 2);

    if (hh >= NH_ + NKV_) {  // v: just convert
        int kv = hh - NH_ - NKV_;
        __hip_bfloat16* o = vb + ((size_t)(b * NKV_ + kv) * T_ + t) * HD_ + lane * 2;
        o[0] = __float2bfloat16(xv.x); o[1] = __float2bfloat16(xv.y);
        return;
    }

    float ss = xv.x * xv.x + xv.y * xv.y;
    #pragma unroll
    for (int off = 32; off; off >>= 1) ss += __shfl_xor(ss, off);
    float rn = rsqrtf(ss * (1.0f / HD_) + 1.1920929e-7f);
    float y0 = xv.x * rn, y1 = xv.y * rn;

    float py0 = __shfl_xor(y0, 4), py1 = __shfl_xor(y1, 4);
    float o0 = y0, o1 = y1;
    if (lane < 8) {
        int i0 = (2 * lane) & 7;
        float f0 = (float)t * exp2f(-(float)i0       * 1.66096404744368f);
        float f1 = (float)t * exp2f(-(float)(i0 + 1) * 1.66096404744368f);
        float s0, c0, s1, c1;
        sincosf(f0, &s0, &c0);
        sincosf(f1, &s1, &c1);
        if (lane < 4) { o0 =  y0 * c0 + py0 * s0; o1 =  y1 * c1 + py1 * s1; }
        else          { o0 = -y0 * c0 + py0 * s0; o1 = -y1 * c1 + py1 * s1; }
    }

    if (hh < NH_) {
        // fold gain * 1/sqrt(HD) * log2(e) into q
        float g = qg[hh] * 0.1275174305f;
        o0 *= g; o1 *= g;
        __hip_bfloat16* o = qb + ((size_t)(b * NH_ + hh) * T_ + t) * HD_ + lane * 2;
        o[0] = __float2bfloat16(o0); o[1] = __float2bfloat16(o1);
    } else {
        int kv = hh - NH_;
        __hip_bfloat16* o = kb + ((size_t)(b * NKV_ + kv) * T_ + t) * HD_ + lane * 2;
        o[0] = __float2bfloat16(o0); o[1] = __float2bfloat16(o1);
    }
}

// ---------------- V transpose: [bk][T][HD] -> [bk][HD][T] ----------------
__global__ void vtrans(const __hip_bfloat16* __restrict__ vb, __hip_bfloat16* __restrict__ vt) {
    __shared__ __hip_bfloat16 tile[32][33];
    int bk = blockIdx.z;
    int t0 = blockIdx.x * 32, h0 = blockIdx.y * 32;
    int tx = threadIdx.x, ty = threadIdx.y;  // 32 x 8
    const __hip_bfloat16* src = vb + ((size_t)bk * T_ + t0) * HD_ + h0;
    #pragma unroll
    for (int j = 0; j < 4; j++) tile[ty + j * 8][tx] = src[(size_t)(ty + j * 8) * HD_ + tx];
    __syncthreads();
    __hip_bfloat16* dst = vt + ((size_t)bk * HD_ + h0) * T_ + t0;
    #pragma unroll
    for (int j = 0; j < 4; j++) dst[(size_t)(ty + j * 8) * T_ + tx] = tile[tx][ty + j * 8];
}

// ---------------- causal GQA flash attention (unchanged from R7) ----------------
__device__ __forceinline__ unsigned pkbf(float a, float b) {
    __hip_bfloat16 x = __float2bfloat16(a), y = __float2bfloat16(b);
    unsigned short xu = *(const unsigned short*)&x, yu = *(const unsigned short*)&y;
    return (unsigned)xu | ((unsigned)yu << 16);
}

union U8u { unsigned u[4]; bf16x8 v; };

__global__ __launch_bounds__(512, 2)
void attn_fwd(const __hip_bfloat16* __restrict__ qb, const __hip_bfloat16* __restrict__ kb,
              const __hip_bfloat16* __restrict__ vt, __hip_bfloat16* __restrict__ yb) {
    __shared__ __attribute__((aligned(16))) __hip_bfloat16 Ks[2][4][4096];  // 64KB
    __shared__ __attribute__((aligned(16))) __hip_bfloat16 Vs[2][4][4096];  // 64KB
    const int tid  = threadIdx.x;
    const int w    = tid >> 6, lane = tid & 63;
    const int l31  = lane & 31, hi = lane >> 5;
    const int hd4  = w & 3;                // head within kv group
    const int seg  = w >> 2;               // KV segment 0/1
    const int bid  = blockIdx.x;
    const int strm = bid & 7;              // = b*4 + kvh (XCD-grouped K/V stream)
    const int b    = strm >> 2, kvh = strm & 3;
    const int idx  = bid >> 3;             // 0..63
    const int c    = (idx < 32) ? (63 - 2 * idx) : (126 - 2 * idx);
    const int ns   = (c >> 1) + 1;         // iters per segment
    const int h    = kvh * 4 + hd4;
    const int qa   = c * 32;

    const __hip_bfloat16* qp = qb + ((size_t)(b * NH_ + h) * T_ + qa) * HD_;
    const __hip_bfloat16* kp = kb + (size_t)(b * NKV_ + kvh) * T_ * HD_;
    const __hip_bfloat16* vp = vt + (size_t)(b * NKV_ + kvh) * HD_ * T_;

    const int tt = tid & 255, sg = tid >> 8;
    const int k_hs = tt >> 5, k_kv = tt & 31;
    const int v_kg = tt >> 7, v_d  = tt & 127;
    const __hip_bfloat16* ksrc0 = kp + (size_t)k_kv * HD_ + k_hs * 8;
    const __hip_bfloat16* ksrc1 = kp + (size_t)k_kv * HD_ + (8 + k_hs) * 8;
    const __hip_bfloat16* vsrc0 = vp + (size_t)v_d * T_ + v_kg * 8;
    const __hip_bfloat16* vsrc1 = vp + (size_t)v_d * T_ + (2 + v_kg) * 8;

    auto stage = [&](int u) {
        int kt0 = u < ns - 1 ? u : ns - 1;
        int kt1 = ns + u; if (kt1 > c) kt1 = c;
        const int kvb = (sg ? kt1 : kt0) * 32;
        const int slot = u & 3;
        __hip_bfloat16* kd = &Ks[sg][slot][(tt >> 6) * 512];
        __hip_bfloat16* vd = &Vs[sg][slot][(tt >> 6) * 512];
        gload_lds16(ksrc0 + (size_t)kvb * HD_, kd);
        gload_lds16(ksrc1 + (size_t)kvb * HD_, kd + 2048);
        gload_lds16(vsrc0 + kvb,               vd);
        gload_lds16(vsrc1 + kvb,               vd + 2048);
    };

    bf16x8 qfr[8];
    #pragma unroll
    for (int hb = 0; hb < 8; ++hb)
        qfr[hb] = *(const bf16x8*)(qp + (size_t)l31 * HD_ + hb * 16 + hi * 8);

    f32x16 o0 = {}, o1 = {}, o2 = {}, o3 = {};
    float m = -1e30f, s = 0.f;

    stage(0);
    stage(1);

    for (int t = 0; t < ns; ++t) {
        stage(t + 2);
        asm volatile("s_waitcnt vmcnt(8)" ::: "memory");
        __builtin_amdgcn_s_barrier();
        __builtin_amdgcn_sched_barrier(0);

        const int kt_raw = seg ? ns + t : t;
        const bool dead  = kt_raw > c;
        const int kt     = dead ? c : kt_raw;

        const __hip_bfloat16* Kb = &Ks[seg][t & 3][0];
        const __hip_bfloat16* Vb = &Vs[seg][t & 3][0];

        f32x16 sa_a = {}, sa_b = {};
        __builtin_amdgcn_s_setprio(1);
        #pragma unroll
        for (int hb = 0; hb < 4; ++hb) {
            bf16x8 kf = *(const bf16x8*)&Kb[((hb * 2 + hi) * 32 + l31) * 8];
            sa_a = __builtin_amdgcn_mfma_f32_32x32x16_bf16(kf, qfr[hb], sa_a, 0, 0, 0);
        }
        #pragma unroll
        for (int hb = 4; hb < 8; ++hb) {
            bf16x8 kf = *(const bf16x8*)&Kb[((hb * 2 + hi) * 32 + l31) * 8];
            sa_b = __builtin_amdgcn_mfma_f32_32x32x16_bf16(kf, qfr[hb], sa_b, 0, 0, 0);
        }
        __builtin_amdgcn_s_setprio(0);
        f32x16 sa = sa_a + sa_b;

        if (dead) {
            #pragma unroll
            for (int r = 0; r < 16; ++r) sa[r] = -1e30f;
        } else if (kt == c) {
            #pragma unroll
            for (int r = 0; r < 16; ++r) {
                int kvrel = (r & 3) + 8 * (r >> 2) + 4 * hi;
                if (kvrel > l31) sa[r] = -1e30f;
            }
        }
        float pm = sa[0];
        #pragma unroll
        for (int r = 1; r < 16; ++r) pm = fmaxf(pm, sa[r]);
        pm = fmaxf(pm, __shfl_xor(pm, 32));
        if (!__all(pm <= m + 8.f)) {
            float mn = fmaxf(m, pm);
            float corr = exp2f(m - mn);
            s *= corr;
            #pragma unroll
            for (int r = 0; r < 16; ++r) { o0[r] *= corr; o1[r] *= corr; o2[r] *= corr; o3[r] *= corr; }
            m = mn;
        }
        float p[16]; float rs = 0.f;
        #pragma unroll
        for (int r = 0; r < 16; ++r) { p[r] = exp2f(sa[r] - m); rs += p[r]; }
        rs += __shfl_xor(rs, 32);
        s += rs;
        unsigned pk[8];
        #pragma unroll
        for (int jj = 0; jj < 8; ++jj) pk[jj] = pkbf(p[2 * jj], p[2 * jj + 1]);
        unsigned pks[8];
        #pragma unroll
        for (int jj = 0; jj < 8; ++jj) pks[jj] = (unsigned)__shfl_xor((int)pk[jj], 32);
        U8u pa0, pa1;
        pa0.u[0] = hi ? pks[2] : pk[0];
        pa0.u[1] = hi ? pks[3] : pk[1];
        pa0.u[2] = hi ? pk[2]  : pks[0];
        pa0.u[3] = hi ? pk[3]  : pks[1];
        pa1.u[0] = hi ? pks[6] : pk[4];
        pa1.u[1] = hi ? pks[7] : pk[5];
        pa1.u[2] = hi ? pk[6]  : pks[4];
        pa1.u[3] = hi ? pk[7]  : pks[5];
        __builtin_amdgcn_s_setprio(1);
        #define PV_BLK(ON, DBLK)                                                              \
            {                                                                                 \
                bf16x8 vf0 = *(const bf16x8*)&Vb[((0 + hi) * 128 + (DBLK) * 32 + l31) * 8];   \
                bf16x8 vf1 = *(const bf16x8*)&Vb[((2 + hi) * 128 + (DBLK) * 32 + l31) * 8];   \
                ON = __builtin_amdgcn_mfma_f32_32x32x16_bf16(vf0, pa0.v, ON, 0, 0, 0);        \
                ON = __builtin_amdgcn_mfma_f32_32x32x16_bf16(vf1, pa1.v, ON, 0, 0, 0);        \
            }
        PV_BLK(o0, 0) PV_BLK(o1, 1) PV_BLK(o2, 2) PV_BLK(o3, 3)
        #undef PV_BLK
        __builtin_amdgcn_s_setprio(0);
    }

    // ---- merge seg1 -> seg0 through LDS (reuse staging space) ----
    asm volatile("s_waitcnt vmcnt(0)" ::: "memory");
    __syncthreads();
    float* Mh = (hd4 < 2) ? ((float*)&Ks[0][0][0] + hd4 * 4352)
                          : ((float*)&Vs[0][0][0] + (hd4 - 2) * 4352);
    if (seg == 1) {
        #pragma unroll
        for (int r = 0; r < 16; ++r) {
            Mh[(0 * 16 + r) * 64 + lane] = o0[r];
            Mh[(1 * 16 + r) * 64 + lane] = o1[r];
            Mh[(2 * 16 + r) * 64 + lane] = o2[r];
            Mh[(3 * 16 + r) * 64 + lane] = o3[r];
        }
        Mh[4096 + lane] = m;
        Mh[4160 + lane] = s;
    }
    __syncthreads();
    if (seg == 0) {
        float m1 = Mh[4096 + lane], s1 = Mh[4160 + lane];
        float mn = fmaxf(m, m1);
        float ca = exp2f(m - mn), cb = exp2f(m1 - mn);
        s = s * ca + s1 * cb;
        #pragma unroll
        for (int r = 0; r < 16; ++r) {
            o0[r] = o0[r] * ca + Mh[(0 * 16 + r) * 64 + lane] * cb;
            o1[r] = o1[r] * ca + Mh[(1 * 16 + r) * 64 + lane] * cb;
            o2[r] = o2[r] * ca + Mh[(2 * 16 + r) * 64 + lane] * cb;
            o3[r] = o3[r] * ca + Mh[(3 * 16 + r) * 64 + lane] * cb;
        }
        float inv = 1.0f / s;
        __hip_bfloat16* yrow = yb + ((size_t)b * T_ + qa + l31) * D_ + h * HD_;
        #define WRITE_DB(ON, DB)                                                        \
            _Pragma("unroll")                                                           \
            for (int r4 = 0; r4 < 4; ++r4) {                                            \
                ushort4 u;                                                              \
                __hip_bfloat16 e0 = __float2bfloat16(ON[4*r4+0] * inv);                 \
                __hip_bfloat16 e1 = __float2bfloat16(ON[4*r4+1] * inv);                 \
                __hip_bfloat16 e2 = __float2bfloat16(ON[4*r4+2] * inv);                 \
                __hip_bfloat16 e3 = __float2bfloat16(ON[4*r4+3] * inv);                 \
                u.x = *(const unsigned short*)&e0; u.y = *(const unsigned short*)&e1;   \
                u.z = *(const unsigned short*)&e2; u.w = *(const unsigned short*)&e3;   \
                *(ushort4*)(yrow + (DB) * 32 + 8 * r4 + 4 * hi) = u;                    \
            }
        WRITE_DB(o0, 0) WRITE_DB(o1, 1) WRITE_DB(o2, 2) WRITE_DB(o3, 3)
        #undef WRITE_DB
    }
}

extern "C" void kernel_launch(void* const* d_in, const int* in_sizes, int n_in,
                              void* d_out, int out_size, void* d_ws, size_t ws_size,
                              hipStream_t stream) {
    (void)in_sizes; (void)n_in; (void)out_size; (void)ws_size;
    const float* x  = (const float*)d_in[0];
    const float* wq = (const float*)d_in[1];
    const float* wk = (const float*)d_in[2];
    const float* wv = (const float*)d_in[3];
    const float* wp = (const float*)d_in[4];
    const float* qg = (const float*)d_in[5];
    float* out = (float*)d_out;

    char* ws = (char*)d_ws;
    size_t off = 0;
    auto alloc = [&](size_t bytes) { char* p = ws + off; off += (bytes + 255) & ~(size_t)255; return p; };

    __hip_bfloat16* xb  = (__hip_bfloat16*)alloc((size_t)BT_ * D_ * 2);
    __hip_bfloat16* wqb = (__hip_bfloat16*)alloc((size_t)D_ * D_ * 2);
    __hip_bfloat16* wkb = (__hip_bfloat16*)alloc((size_t)KD_ * D_ * 2);
    __hip_bfloat16* wvb = (__hip_bfloat16*)alloc((size_t)KD_ * D_ * 2);
    __hip_bfloat16* wpb = (__hip_bfloat16*)alloc((size_t)D_ * D_ * 2);
    float* qf = (float*)alloc((size_t)BT_ * D_ * 4);
    float* kf = (float*)alloc((size_t)BT_ * KD_ * 4);
    float* vf = (float*)alloc((size_t)BT_ * KD_ * 4);
    __hip_bfloat16* qbb = (__hip_bfloat16*)alloc((size_t)BT_ * D_ * 2);
    __hip_bfloat16* kbb = (__hip_bfloat16*)alloc((size_t)BT_ * KD_ * 2);
    // aliases (lifetimes disjoint on the sequential stream):
    __hip_bfloat16* ybb = xb;                   // yb written after xb's last read
    __hip_bfloat16* vbb = wqb;                  // wqb dead after q-projection
    __hip_bfloat16* vtb = wqb + (size_t)B_ * NKV_ * T_ * HD_;

    f2b_all<<<2048, 256, 0, stream>>>((const float4*)x, (const float4*)wq, (const float4*)wk,
                                      (const float4*)wv, (const float4*)wp,
                                      (ushort4*)xb, (ushort4*)wqb, (ushort4*)wkb,
                                      (ushort4*)wvb, (ushort4*)wpb);

    // fused q/k/v projections: one launch, 32 x 24 = 768 blocks
    dim3 gqkv(BT_ / 128, 24);
    gemm_qkv<<<gqkv, 256, 0, stream>>>(xb, wqb, wkb, wvb, qf, kf, vf);

    norm_rope<<<(BT_ * 24) / 4, 256, 0, stream>>>(qf, kf, vf, qg, qbb, kbb, vbb);

    dim3 gt(T_ / 32, HD_ / 32, B_ * NKV_);
    vtrans<<<gt, dim3(32, 8), 0, stream>>>(vbb, vtb);

    attn_fwd<<<512, 512, 0, stream>>>(qbb, kbb, vtb, ybb);

    // output projection
    dim3 gq(BT_ / 128, D_ / 128);
    gemm_p<<<gq, 256, 0, stream>>>(ybb, wpb, out, D_, D_);
}